// Round 2
// baseline (2943.612 us; speedup 1.0000x reference)
//
#include <hip/hip_runtime.h>
#include <hip/hip_bf16.h>
#include <math.h>

#define D_MODEL   1024
#define D_INNER   2048
#define HEADDIM   64
#define NHEADS    32
#define D_STATE   128
#define D_CONV    4
#define CONV_DIM  (D_INNER + 2 * D_STATE)          // 2304
#define D_IN_PROJ (2 * D_INNER + 2 * D_STATE + NHEADS) // 4384
#define BATCH     2
#define SEQLEN    2048
#define BL        (BATCH * SEQLEN)                 // 4096
#define EPS       1e-5f

__device__ __forceinline__ float siluf(float x) {
    return x / (1.0f + expf(-x));
}
__device__ __forceinline__ float softplusf(float x) {
    return (x > 20.0f) ? x : log1pf(expf(x));
}

// ---------------------------------------------------------------------------
// Generic fp32 GEMM: C[m,n] = sum_k A[m,k] * B[n,k]   (A: MxK, B: NxK, both
// row-major K-contiguous).  64x64 tile, BK=16, 256 threads, 4x4 microtile.
// M, K assumed divisible by 64/16; N guarded.
// ---------------------------------------------------------------------------
#define BM 64
#define BN 64
#define BK 16

__global__ __launch_bounds__(256) void gemm_nt(
    const float* __restrict__ A, const float* __restrict__ B,
    float* __restrict__ C, int M, int N, int K)
{
    __shared__ __align__(16) float As[BK][BM + 4];  // [k][m]
    __shared__ __align__(16) float Bs[BK][BN + 4];  // [k][n]

    const int bm = blockIdx.y * BM;
    const int bn = blockIdx.x * BN;
    const int tid = threadIdx.x;
    const int tx = tid & 15;        // n dir
    const int ty = tid >> 4;        // m dir

    const int lrow = tid >> 2;          // 0..63
    const int lcol = (tid & 3) * 4;     // 0,4,8,12

    float acc[4][4] = {};

    for (int k0 = 0; k0 < K; k0 += BK) {
        float4 a4 = *reinterpret_cast<const float4*>(
            &A[(size_t)(bm + lrow) * K + k0 + lcol]);
        float4 b4;
        const int brow = bn + lrow;
        if (brow < N) {
            b4 = *reinterpret_cast<const float4*>(
                &B[(size_t)brow * K + k0 + lcol]);
        } else {
            b4 = make_float4(0.f, 0.f, 0.f, 0.f);
        }
        __syncthreads();
        As[lcol + 0][lrow] = a4.x;
        As[lcol + 1][lrow] = a4.y;
        As[lcol + 2][lrow] = a4.z;
        As[lcol + 3][lrow] = a4.w;
        Bs[lcol + 0][lrow] = b4.x;
        Bs[lcol + 1][lrow] = b4.y;
        Bs[lcol + 2][lrow] = b4.z;
        Bs[lcol + 3][lrow] = b4.w;
        __syncthreads();

        #pragma unroll
        for (int k = 0; k < BK; ++k) {
            float4 ar = *reinterpret_cast<const float4*>(&As[k][ty * 4]);
            float4 br = *reinterpret_cast<const float4*>(&Bs[k][tx * 4]);
            acc[0][0] += ar.x * br.x; acc[0][1] += ar.x * br.y;
            acc[0][2] += ar.x * br.z; acc[0][3] += ar.x * br.w;
            acc[1][0] += ar.y * br.x; acc[1][1] += ar.y * br.y;
            acc[1][2] += ar.y * br.z; acc[1][3] += ar.y * br.w;
            acc[2][0] += ar.z * br.x; acc[2][1] += ar.z * br.y;
            acc[2][2] += ar.z * br.z; acc[2][3] += ar.z * br.w;
            acc[3][0] += ar.w * br.x; acc[3][1] += ar.w * br.y;
            acc[3][2] += ar.w * br.z; acc[3][3] += ar.w * br.w;
        }
    }

    #pragma unroll
    for (int i = 0; i < 4; ++i) {
        const int gm = bm + ty * 4 + i;
        #pragma unroll
        for (int j = 0; j < 4; ++j) {
            const int gn = bn + tx * 4 + j;
            if (gn < N) C[(size_t)gm * N + gn] = acc[i][j];
        }
    }
}

// ---------------------------------------------------------------------------
// Causal depthwise conv (K=4) + SiLU over the xBC slice of zxbcdt.
// ---------------------------------------------------------------------------
__global__ __launch_bounds__(256) void conv_silu_kernel(
    const float* __restrict__ zxbcdt, const float* __restrict__ conv_w,
    const float* __restrict__ conv_b, float* __restrict__ xbc_out)
{
    const int idx = blockIdx.x * 256 + threadIdx.x;
    if (idx >= BL * CONV_DIM) return;
    const int c  = idx % CONV_DIM;
    const int bl = idx / CONV_DIM;
    const int l  = bl % SEQLEN;
    const int b  = bl / SEQLEN;

    float acc = conv_b[c];
    #pragma unroll
    for (int k = 0; k < D_CONV; ++k) {
        const int ll = l + k - (D_CONV - 1);
        if (ll >= 0) {
            acc += zxbcdt[(size_t)(b * SEQLEN + ll) * D_IN_PROJ + D_INNER + c]
                   * conv_w[c * D_CONV + k];
        }
    }
    xbc_out[idx] = siluf(acc);
}

// ---------------------------------------------------------------------------
// dt = softplus(dt_raw + dt_bias)
// ---------------------------------------------------------------------------
__global__ __launch_bounds__(256) void dt_kernel(
    const float* __restrict__ zxbcdt, const float* __restrict__ dt_bias,
    float* __restrict__ dt_out)
{
    const int idx = blockIdx.x * 256 + threadIdx.x;
    if (idx >= BL * NHEADS) return;
    const int h  = idx % NHEADS;
    const int bl = idx / NHEADS;
    const float v = zxbcdt[(size_t)bl * D_IN_PROJ + D_INNER + CONV_DIM + h]
                    + dt_bias[h];
    dt_out[idx] = softplusf(v);
}

// ---------------------------------------------------------------------------
// SSD scan.  256 blocks: (b, h, p-quarter).  256 threads: p_local = tid>>4
// (16 p values), n-chunk = tid&15 (8 states each).  State in registers.
// y[b,t,h*64+p] = sum_n h[p,n]*C_t[n] + D[h]*x[b,t,h,p]
// ---------------------------------------------------------------------------
__global__ __launch_bounds__(256) void scan_kernel(
    const float* __restrict__ xbc,    // (BL, CONV_DIM)  post conv+silu
    const float* __restrict__ dt,     // (BL, NHEADS)    post softplus
    const float* __restrict__ A_log,
    const float* __restrict__ Dp,
    float* __restrict__ y)            // (BL, D_INNER)
{
    const int blk = blockIdx.x;
    const int pq  = blk & 3;
    const int h   = (blk >> 2) & 31;
    const int b   = blk >> 7;
    const int tid = threadIdx.x;
    const int pl  = tid >> 4;       // 0..15
    const int nc  = tid & 15;       // 0..15
    const int n0  = nc * 8;

    const float A_h = -expf(A_log[h]);
    const float D_h = Dp[h];

    float hs[8] = {0.f, 0.f, 0.f, 0.f, 0.f, 0.f, 0.f, 0.f};

    __shared__ float Bs[D_STATE];
    __shared__ float Cs[D_STATE];
    __shared__ float Xs[16];

    const float* xbc_b = xbc + (size_t)b * SEQLEN * CONV_DIM;
    const int p_out = h * HEADDIM + pq * 16 + pl;

    for (int t = 0; t < SEQLEN; ++t) {
        const float* row = xbc_b + (size_t)t * CONV_DIM;
        __syncthreads();
        if (tid < D_STATE) {
            Bs[tid] = row[D_INNER + tid];
        } else {
            Cs[tid - D_STATE] = row[D_INNER + D_STATE + (tid - D_STATE)];
        }
        if (tid < 16) Xs[tid] = row[h * HEADDIM + pq * 16 + tid];
        __syncthreads();

        const float dtv = dt[((size_t)b * SEQLEN + t) * NHEADS + h];
        const float dA  = expf(A_h * dtv);
        const float dtx = dtv * Xs[pl];

        float acc = 0.f;
        #pragma unroll
        for (int i = 0; i < 8; ++i) {
            hs[i] = hs[i] * dA + dtx * Bs[n0 + i];
            acc += hs[i] * Cs[n0 + i];
        }
        acc += __shfl_xor(acc, 1, 64);
        acc += __shfl_xor(acc, 2, 64);
        acc += __shfl_xor(acc, 4, 64);
        acc += __shfl_xor(acc, 8, 64);
        if (nc == 0) {
            y[((size_t)b * SEQLEN + t) * D_INNER + p_out] = acc + D_h * Xs[pl];
        }
    }
}

// ---------------------------------------------------------------------------
// yg = y * silu(z); rmsnorm(yg) * norm_w  (in-place on y).  One block per row.
// ---------------------------------------------------------------------------
__global__ __launch_bounds__(256) void gate_norm_kernel(
    float* __restrict__ y,                 // (BL, D_INNER), in/out
    const float* __restrict__ zxbcdt,      // z at offset 0
    const float* __restrict__ norm_w)
{
    const int row = blockIdx.x;
    const int tid = threadIdx.x;
    float* yr = y + (size_t)row * D_INNER;
    const float* zr = zxbcdt + (size_t)row * D_IN_PROJ;

    float v[8];
    float ss = 0.f;
    #pragma unroll
    for (int j = 0; j < 2; ++j) {
        float4 y4 = *reinterpret_cast<const float4*>(&yr[tid * 8 + j * 4]);
        float4 z4 = *reinterpret_cast<const float4*>(&zr[tid * 8 + j * 4]);
        float a0 = y4.x * siluf(z4.x);
        float a1 = y4.y * siluf(z4.y);
        float a2 = y4.z * siluf(z4.z);
        float a3 = y4.w * siluf(z4.w);
        v[j * 4 + 0] = a0; v[j * 4 + 1] = a1;
        v[j * 4 + 2] = a2; v[j * 4 + 3] = a3;
        ss += a0 * a0 + a1 * a1 + a2 * a2 + a3 * a3;
    }
    #pragma unroll
    for (int o = 1; o < 64; o <<= 1) ss += __shfl_xor(ss, o, 64);
    __shared__ float red[4];
    if ((tid & 63) == 0) red[tid >> 6] = ss;
    __syncthreads();
    const float tot = red[0] + red[1] + red[2] + red[3];
    const float rs = rsqrtf(tot * (1.0f / D_INNER) + EPS);

    #pragma unroll
    for (int j = 0; j < 2; ++j) {
        float4 o4;
        o4.x = v[j * 4 + 0] * rs * norm_w[tid * 8 + j * 4 + 0];
        o4.y = v[j * 4 + 1] * rs * norm_w[tid * 8 + j * 4 + 1];
        o4.z = v[j * 4 + 2] * rs * norm_w[tid * 8 + j * 4 + 2];
        o4.w = v[j * 4 + 3] * rs * norm_w[tid * 8 + j * 4 + 3];
        *reinterpret_cast<float4*>(&yr[tid * 8 + j * 4]) = o4;
    }
}

// ---------------------------------------------------------------------------
extern "C" void kernel_launch(void* const* d_in, const int* in_sizes, int n_in,
                              void* d_out, int out_size, void* d_ws, size_t ws_size,
                              hipStream_t stream)
{
    const float* u       = (const float*)d_in[0];
    const float* W_in    = (const float*)d_in[1];
    const float* conv_w  = (const float*)d_in[2];
    const float* conv_b  = (const float*)d_in[3];
    const float* dt_bias = (const float*)d_in[4];
    const float* A_log   = (const float*)d_in[5];
    const float* Dp      = (const float*)d_in[6];
    const float* norm_w  = (const float*)d_in[7];
    const float* W_out   = (const float*)d_in[8];
    float* out = (float*)d_out;

    float* zxbcdt = (float*)d_ws;
    float* xbc    = zxbcdt + (size_t)BL * D_IN_PROJ;
    float* dt_sp  = xbc    + (size_t)BL * CONV_DIM;
    float* yb     = dt_sp  + (size_t)BL * NHEADS;

    // 1. in-projection GEMM: zxbcdt (4096 x 4384) = u (4096x1024) @ W_in^T
    {
        dim3 grid((D_IN_PROJ + BN - 1) / BN, BL / BM);
        gemm_nt<<<grid, 256, 0, stream>>>(u, W_in, zxbcdt, BL, D_IN_PROJ, D_MODEL);
    }
    // 2. causal depthwise conv + SiLU
    {
        const int n = BL * CONV_DIM;
        conv_silu_kernel<<<(n + 255) / 256, 256, 0, stream>>>(zxbcdt, conv_w, conv_b, xbc);
    }
    // 3. dt = softplus(dt_raw + bias)
    {
        const int n = BL * NHEADS;
        dt_kernel<<<(n + 255) / 256, 256, 0, stream>>>(zxbcdt, dt_bias, dt_sp);
    }
    // 4. SSD scan
    scan_kernel<<<256, 256, 0, stream>>>(xbc, dt_sp, A_log, Dp, yb);
    // 5. gate + RMSNorm (in-place on yb)
    gate_norm_kernel<<<BL, 256, 0, stream>>>(yb, zxbcdt, norm_w);
    // 6. out-projection GEMM: out (4096 x 1024) = yb (4096x2048) @ W_out^T
    {
        dim3 grid(D_MODEL / BN, BL / BM);
        gemm_nt<<<grid, 256, 0, stream>>>(yb, W_out, out, BL, D_MODEL, D_INNER);
    }
}

// Round 4
// 1313.178 us; speedup vs baseline: 2.2416x; 2.2416x over previous
//
#include <hip/hip_runtime.h>
#include <hip/hip_bf16.h>
#include <math.h>

#define D_MODEL   1024
#define D_INNER   2048
#define HEADDIM   64
#define NHEADS    32
#define D_STATE   128
#define D_CONV    4
#define CONV_DIM  (D_INNER + 2 * D_STATE)          // 2304
#define D_IN_PROJ (2 * D_INNER + 2 * D_STATE + NHEADS) // 4384
#define BATCH     2
#define SEQLEN    2048
#define BL        (BATCH * SEQLEN)                 // 4096
#define EPS       1e-5f

#define NC    16          // number of chunks
#define CHUNK 128         // SEQLEN / NC

__device__ __forceinline__ float siluf(float x) {
    return x / (1.0f + expf(-x));
}
__device__ __forceinline__ float softplusf(float x) {
    return (x > 20.0f) ? x : log1pf(expf(x));
}

// ---------------------------------------------------------------------------
// Generic fp32 GEMM: C[m,n] = sum_k A[m,k] * B[n,k]
// ---------------------------------------------------------------------------
#define BM 64
#define BN 64
#define BK 16

__global__ __launch_bounds__(256) void gemm_nt(
    const float* __restrict__ A, const float* __restrict__ B,
    float* __restrict__ C, int M, int N, int K)
{
    __shared__ __align__(16) float As[BK][BM + 4];
    __shared__ __align__(16) float Bs[BK][BN + 4];

    const int bm = blockIdx.y * BM;
    const int bn = blockIdx.x * BN;
    const int tid = threadIdx.x;
    const int tx = tid & 15;
    const int ty = tid >> 4;

    const int lrow = tid >> 2;
    const int lcol = (tid & 3) * 4;

    float acc[4][4] = {};

    for (int k0 = 0; k0 < K; k0 += BK) {
        float4 a4 = *reinterpret_cast<const float4*>(
            &A[(size_t)(bm + lrow) * K + k0 + lcol]);
        float4 b4;
        const int brow = bn + lrow;
        if (brow < N) {
            b4 = *reinterpret_cast<const float4*>(
                &B[(size_t)brow * K + k0 + lcol]);
        } else {
            b4 = make_float4(0.f, 0.f, 0.f, 0.f);
        }
        __syncthreads();
        As[lcol + 0][lrow] = a4.x;
        As[lcol + 1][lrow] = a4.y;
        As[lcol + 2][lrow] = a4.z;
        As[lcol + 3][lrow] = a4.w;
        Bs[lcol + 0][lrow] = b4.x;
        Bs[lcol + 1][lrow] = b4.y;
        Bs[lcol + 2][lrow] = b4.z;
        Bs[lcol + 3][lrow] = b4.w;
        __syncthreads();

        #pragma unroll
        for (int k = 0; k < BK; ++k) {
            float4 ar = *reinterpret_cast<const float4*>(&As[k][ty * 4]);
            float4 br = *reinterpret_cast<const float4*>(&Bs[k][tx * 4]);
            acc[0][0] += ar.x * br.x; acc[0][1] += ar.x * br.y;
            acc[0][2] += ar.x * br.z; acc[0][3] += ar.x * br.w;
            acc[1][0] += ar.y * br.x; acc[1][1] += ar.y * br.y;
            acc[1][2] += ar.y * br.z; acc[1][3] += ar.y * br.w;
            acc[2][0] += ar.z * br.x; acc[2][1] += ar.z * br.y;
            acc[2][2] += ar.z * br.z; acc[2][3] += ar.z * br.w;
            acc[3][0] += ar.w * br.x; acc[3][1] += ar.w * br.y;
            acc[3][2] += ar.w * br.z; acc[3][3] += ar.w * br.w;
        }
    }

    #pragma unroll
    for (int i = 0; i < 4; ++i) {
        const int gm = bm + ty * 4 + i;
        #pragma unroll
        for (int j = 0; j < 4; ++j) {
            const int gn = bn + tx * 4 + j;
            if (gn < N) C[(size_t)gm * N + gn] = acc[i][j];
        }
    }
}

// ---------------------------------------------------------------------------
// Causal depthwise conv (K=4) + SiLU over the xBC slice of zxbcdt.
// ---------------------------------------------------------------------------
__global__ __launch_bounds__(256) void conv_silu_kernel(
    const float* __restrict__ zxbcdt, const float* __restrict__ conv_w,
    const float* __restrict__ conv_b, float* __restrict__ xbc_out)
{
    const int idx = blockIdx.x * 256 + threadIdx.x;
    if (idx >= BL * CONV_DIM) return;
    const int c  = idx % CONV_DIM;
    const int bl = idx / CONV_DIM;
    const int l  = bl % SEQLEN;
    const int b  = bl / SEQLEN;

    float acc = conv_b[c];
    #pragma unroll
    for (int k = 0; k < D_CONV; ++k) {
        const int ll = l + k - (D_CONV - 1);
        if (ll >= 0) {
            acc += zxbcdt[(size_t)(b * SEQLEN + ll) * D_IN_PROJ + D_INNER + c]
                   * conv_w[c * D_CONV + k];
        }
    }
    xbc_out[idx] = siluf(acc);
}

// ---------------------------------------------------------------------------
// dt = softplus(dt_raw + dt_bias)
// ---------------------------------------------------------------------------
__global__ __launch_bounds__(256) void dt_kernel(
    const float* __restrict__ zxbcdt, const float* __restrict__ dt_bias,
    float* __restrict__ dt_out)
{
    const int idx = blockIdx.x * 256 + threadIdx.x;
    if (idx >= BL * NHEADS) return;
    const int h  = idx % NHEADS;
    const int bl = idx / NHEADS;
    const float v = zxbcdt[(size_t)bl * D_IN_PROJ + D_INNER + CONV_DIM + h]
                    + dt_bias[h];
    dt_out[idx] = softplusf(v);
}

// ---------------------------------------------------------------------------
// Chunked SSD scan.
// State decomposition: h_t = dA_t h_{t-1} + dt_t x_t B_t^T, y_t = C_t.h_t + D x_t
// Phase A: per-chunk local end state S_c (zero init), alpha_c = exp(A*sum dt)
// Phase B: sequential over NC chunks (in-place: S_c <- H_c = chunk-start state)
// Phase C: re-scan chunk from H_c, emit y.
// Block (c,b,h,pq): 256 thr, thread owns p = pq*16 + (tid>>4), n in
// [(tid&15)*8, +8).  S layout: S[bid][tid*8..] with bid=((c*2+b)*32+h)*4+pq.
// No LDS, no barriers; explicit register double-buffering of loads.
// ---------------------------------------------------------------------------
struct LBa { float4 b0, b1; float x, d; };

__device__ __forceinline__ void load_a(LBa& L, const float* __restrict__ row,
                                       int xoff, int n0,
                                       const float* __restrict__ dtp, int t) {
    L.b0 = *reinterpret_cast<const float4*>(&row[D_INNER + n0]);
    L.b1 = *reinterpret_cast<const float4*>(&row[D_INNER + n0 + 4]);
    L.x  = row[xoff];
    L.d  = dtp[(size_t)t * NHEADS];
}

__device__ __forceinline__ void step_a(float (&hs)[8], const LBa& L,
                                       float A_h, float& sdt) {
    sdt += L.d;
    const float dA  = __expf(A_h * L.d);
    const float dtx = L.d * L.x;
    hs[0] = hs[0] * dA + dtx * L.b0.x;
    hs[1] = hs[1] * dA + dtx * L.b0.y;
    hs[2] = hs[2] * dA + dtx * L.b0.z;
    hs[3] = hs[3] * dA + dtx * L.b0.w;
    hs[4] = hs[4] * dA + dtx * L.b1.x;
    hs[5] = hs[5] * dA + dtx * L.b1.y;
    hs[6] = hs[6] * dA + dtx * L.b1.z;
    hs[7] = hs[7] * dA + dtx * L.b1.w;
}

__global__ __launch_bounds__(256) void ssd_chunk_state(
    const float* __restrict__ xbc, const float* __restrict__ dt,
    const float* __restrict__ A_log,
    float* __restrict__ S, float* __restrict__ alpha)
{
    const int bid = blockIdx.x;
    const int pq = bid & 3;
    const int h  = (bid >> 2) & 31;
    const int b  = (bid >> 7) & 1;
    const int c  = bid >> 8;
    const int tid = threadIdx.x;
    const int pl = tid >> 4;
    const int n0 = (tid & 15) * 8;
    const int xoff = h * HEADDIM + pq * 16 + pl;

    const float A_h = -__expf(A_log[h]);
    const float* xb  = xbc + (size_t)(b * SEQLEN + c * CHUNK) * CONV_DIM;
    const float* dtp = dt  + (size_t)(b * SEQLEN + c * CHUNK) * NHEADS + h;

    float hs[8] = {};
    float sdt = 0.f;
    LBa La, Lb;
    load_a(La, xb, xoff, n0, dtp, 0);
    for (int t = 0; t < CHUNK; t += 2) {
        load_a(Lb, xb + (size_t)(t + 1) * CONV_DIM, xoff, n0, dtp, t + 1);
        step_a(hs, La, A_h, sdt);
        if (t + 2 < CHUNK)
            load_a(La, xb + (size_t)(t + 2) * CONV_DIM, xoff, n0, dtp, t + 2);
        step_a(hs, Lb, A_h, sdt);
    }
    float* Sp = S + (size_t)bid * 2048 + tid * 8;
    *reinterpret_cast<float4*>(Sp)     = make_float4(hs[0], hs[1], hs[2], hs[3]);
    *reinterpret_cast<float4*>(Sp + 4) = make_float4(hs[4], hs[5], hs[6], hs[7]);
    if (tid == 0 && pq == 0) alpha[(c * 2 + b) * 32 + h] = __expf(A_h * sdt);
}

__global__ __launch_bounds__(256) void ssd_state_scan(
    float* __restrict__ S, const float* __restrict__ alpha)
{
    const int bid = blockIdx.x;       // (b,h,pq)
    const int pq = bid & 3;
    const int h  = (bid >> 2) & 31;
    const int b  = bid >> 7;
    const int tid = threadIdx.x;
    float h0[8] = {};
    #pragma unroll 2
    for (int c = 0; c < NC; ++c) {
        const int sb = ((c * 2 + b) * 32 + h) * 4 + pq;
        float* Sp = S + (size_t)sb * 2048 + tid * 8;
        const float al = alpha[(c * 2 + b) * 32 + h];
        float4 t0 = *reinterpret_cast<const float4*>(Sp);
        float4 t1 = *reinterpret_cast<const float4*>(Sp + 4);
        *reinterpret_cast<float4*>(Sp)     = make_float4(h0[0], h0[1], h0[2], h0[3]);
        *reinterpret_cast<float4*>(Sp + 4) = make_float4(h0[4], h0[5], h0[6], h0[7]);
        h0[0] = h0[0] * al + t0.x;
        h0[1] = h0[1] * al + t0.y;
        h0[2] = h0[2] * al + t0.z;
        h0[3] = h0[3] * al + t0.w;
        h0[4] = h0[4] * al + t1.x;
        h0[5] = h0[5] * al + t1.y;
        h0[6] = h0[6] * al + t1.z;
        h0[7] = h0[7] * al + t1.w;
    }
}

struct LBc { float4 b0, b1, c0, c1; float x, d; };

__device__ __forceinline__ void load_c(LBc& L, const float* __restrict__ row,
                                       int xoff, int n0,
                                       const float* __restrict__ dtp, int t) {
    L.b0 = *reinterpret_cast<const float4*>(&row[D_INNER + n0]);
    L.b1 = *reinterpret_cast<const float4*>(&row[D_INNER + n0 + 4]);
    L.c0 = *reinterpret_cast<const float4*>(&row[D_INNER + D_STATE + n0]);
    L.c1 = *reinterpret_cast<const float4*>(&row[D_INNER + D_STATE + n0 + 4]);
    L.x  = row[xoff];
    L.d  = dtp[(size_t)t * NHEADS];
}

__device__ __forceinline__ float step_c(float (&hs)[8], const LBc& L, float A_h) {
    const float dA  = __expf(A_h * L.d);
    const float dtx = L.d * L.x;
    float acc;
    hs[0] = hs[0] * dA + dtx * L.b0.x;  acc  = hs[0] * L.c0.x;
    hs[1] = hs[1] * dA + dtx * L.b0.y;  acc += hs[1] * L.c0.y;
    hs[2] = hs[2] * dA + dtx * L.b0.z;  acc += hs[2] * L.c0.z;
    hs[3] = hs[3] * dA + dtx * L.b0.w;  acc += hs[3] * L.c0.w;
    hs[4] = hs[4] * dA + dtx * L.b1.x;  acc += hs[4] * L.c1.x;
    hs[5] = hs[5] * dA + dtx * L.b1.y;  acc += hs[5] * L.c1.y;
    hs[6] = hs[6] * dA + dtx * L.b1.z;  acc += hs[6] * L.c1.z;
    hs[7] = hs[7] * dA + dtx * L.b1.w;  acc += hs[7] * L.c1.w;
    return acc;
}

__global__ __launch_bounds__(256) void ssd_chunk_out(
    const float* __restrict__ xbc, const float* __restrict__ dt,
    const float* __restrict__ A_log, const float* __restrict__ Dp,
    const float* __restrict__ S, float* __restrict__ y)
{
    const int bid = blockIdx.x;
    const int pq = bid & 3;
    const int h  = (bid >> 2) & 31;
    const int b  = (bid >> 7) & 1;
    const int c  = bid >> 8;
    const int tid = threadIdx.x;
    const int pl = tid >> 4;
    const int n0 = (tid & 15) * 8;
    const int xoff = h * HEADDIM + pq * 16 + pl;

    const float A_h = -__expf(A_log[h]);
    const float D_h = Dp[h];
    const float* xb  = xbc + (size_t)(b * SEQLEN + c * CHUNK) * CONV_DIM;
    const float* dtp = dt  + (size_t)(b * SEQLEN + c * CHUNK) * NHEADS + h;
    float* yb = y + (size_t)(b * SEQLEN + c * CHUNK) * D_INNER + xoff;

    float hs[8];
    const float* Hp = S + (size_t)bid * 2048 + tid * 8;
    {
        float4 h0 = *reinterpret_cast<const float4*>(Hp);
        float4 h1 = *reinterpret_cast<const float4*>(Hp + 4);
        hs[0] = h0.x; hs[1] = h0.y; hs[2] = h0.z; hs[3] = h0.w;
        hs[4] = h1.x; hs[5] = h1.y; hs[6] = h1.z; hs[7] = h1.w;
    }

    LBc La, Lb;
    load_c(La, xb, xoff, n0, dtp, 0);
    for (int t = 0; t < CHUNK; t += 2) {
        load_c(Lb, xb + (size_t)(t + 1) * CONV_DIM, xoff, n0, dtp, t + 1);
        float acc = step_c(hs, La, A_h);
        acc += __shfl_xor(acc, 1, 64);
        acc += __shfl_xor(acc, 2, 64);
        acc += __shfl_xor(acc, 4, 64);
        acc += __shfl_xor(acc, 8, 64);
        if ((tid & 15) == 0) yb[(size_t)t * D_INNER] = acc + D_h * La.x;
        if (t + 2 < CHUNK)
            load_c(La, xb + (size_t)(t + 2) * CONV_DIM, xoff, n0, dtp, t + 2);
        float acc2 = step_c(hs, Lb, A_h);
        acc2 += __shfl_xor(acc2, 1, 64);
        acc2 += __shfl_xor(acc2, 2, 64);
        acc2 += __shfl_xor(acc2, 4, 64);
        acc2 += __shfl_xor(acc2, 8, 64);
        if ((tid & 15) == 0) yb[(size_t)(t + 1) * D_INNER] = acc2 + D_h * Lb.x;
    }
}

// ---------------------------------------------------------------------------
// yg = y * silu(z); rmsnorm(yg) * norm_w  (in-place on y).  One block per row.
// ---------------------------------------------------------------------------
__global__ __launch_bounds__(256) void gate_norm_kernel(
    float* __restrict__ y,
    const float* __restrict__ zxbcdt,
    const float* __restrict__ norm_w)
{
    const int row = blockIdx.x;
    const int tid = threadIdx.x;
    float* yr = y + (size_t)row * D_INNER;
    const float* zr = zxbcdt + (size_t)row * D_IN_PROJ;

    float v[8];
    float ss = 0.f;
    #pragma unroll
    for (int j = 0; j < 2; ++j) {
        float4 y4 = *reinterpret_cast<const float4*>(&yr[tid * 8 + j * 4]);
        float4 z4 = *reinterpret_cast<const float4*>(&zr[tid * 8 + j * 4]);
        float a0 = y4.x * siluf(z4.x);
        float a1 = y4.y * siluf(z4.y);
        float a2 = y4.z * siluf(z4.z);
        float a3 = y4.w * siluf(z4.w);
        v[j * 4 + 0] = a0; v[j * 4 + 1] = a1;
        v[j * 4 + 2] = a2; v[j * 4 + 3] = a3;
        ss += a0 * a0 + a1 * a1 + a2 * a2 + a3 * a3;
    }
    #pragma unroll
    for (int o = 1; o < 64; o <<= 1) ss += __shfl_xor(ss, o, 64);
    __shared__ float red[4];
    if ((tid & 63) == 0) red[tid >> 6] = ss;
    __syncthreads();
    const float tot = red[0] + red[1] + red[2] + red[3];
    const float rs = rsqrtf(tot * (1.0f / D_INNER) + EPS);

    #pragma unroll
    for (int j = 0; j < 2; ++j) {
        float4 o4;
        o4.x = v[j * 4 + 0] * rs * norm_w[tid * 8 + j * 4 + 0];
        o4.y = v[j * 4 + 1] * rs * norm_w[tid * 8 + j * 4 + 1];
        o4.z = v[j * 4 + 2] * rs * norm_w[tid * 8 + j * 4 + 2];
        o4.w = v[j * 4 + 3] * rs * norm_w[tid * 8 + j * 4 + 3];
        *reinterpret_cast<float4*>(&yr[tid * 8 + j * 4]) = o4;
    }
}

// ---------------------------------------------------------------------------
extern "C" void kernel_launch(void* const* d_in, const int* in_sizes, int n_in,
                              void* d_out, int out_size, void* d_ws, size_t ws_size,
                              hipStream_t stream)
{
    const float* u       = (const float*)d_in[0];
    const float* W_in    = (const float*)d_in[1];
    const float* conv_w  = (const float*)d_in[2];
    const float* conv_b  = (const float*)d_in[3];
    const float* dt_bias = (const float*)d_in[4];
    const float* A_log   = (const float*)d_in[5];
    const float* Dp      = (const float*)d_in[6];
    const float* norm_w  = (const float*)d_in[7];
    const float* W_out   = (const float*)d_in[8];
    float* out = (float*)d_out;

    float* zxbcdt = (float*)d_ws;
    float* xbc    = zxbcdt + (size_t)BL * D_IN_PROJ;
    float* dt_sp  = xbc    + (size_t)BL * CONV_DIM;
    float* yb     = dt_sp  + (size_t)BL * NHEADS;
    float* Sbuf   = yb     + (size_t)BL * D_INNER;
    float* alphab = Sbuf   + (size_t)NC * BATCH * NHEADS * HEADDIM * D_STATE;

    // 1. in-projection GEMM
    {
        dim3 grid((D_IN_PROJ + BN - 1) / BN, BL / BM);
        gemm_nt<<<grid, 256, 0, stream>>>(u, W_in, zxbcdt, BL, D_IN_PROJ, D_MODEL);
    }
    // 2. causal depthwise conv + SiLU
    {
        const int n = BL * CONV_DIM;
        conv_silu_kernel<<<(n + 255) / 256, 256, 0, stream>>>(zxbcdt, conv_w, conv_b, xbc);
    }
    // 3. dt = softplus(dt_raw + bias)
    {
        const int n = BL * NHEADS;
        dt_kernel<<<(n + 255) / 256, 256, 0, stream>>>(zxbcdt, dt_bias, dt_sp);
    }
    // 4. chunked SSD scan: A (per-chunk states) -> B (chunk scan) -> C (outputs)
    ssd_chunk_state<<<NC * BATCH * NHEADS * 4, 256, 0, stream>>>(
        xbc, dt_sp, A_log, Sbuf, alphab);
    ssd_state_scan<<<BATCH * NHEADS * 4, 256, 0, stream>>>(Sbuf, alphab);
    ssd_chunk_out<<<NC * BATCH * NHEADS * 4, 256, 0, stream>>>(
        xbc, dt_sp, A_log, Dp, Sbuf, yb);
    // 5. gate + RMSNorm
    gate_norm_kernel<<<BL, 256, 0, stream>>>(yb, zxbcdt, norm_w);
    // 6. out-projection GEMM
    {
        dim3 grid(D_MODEL / BN, BL / BM);
        gemm_nt<<<grid, 256, 0, stream>>>(yb, W_out, out, BL, D_MODEL, D_INNER);
    }
}

// Round 6
// 704.713 us; speedup vs baseline: 4.1770x; 1.8634x over previous
//
#include <hip/hip_runtime.h>
#include <hip/hip_bf16.h>
#include <math.h>
#include <stdint.h>

#define D_MODEL   1024
#define D_INNER   2048
#define HEADDIM   64
#define NHEADS    32
#define D_STATE   128
#define D_CONV    4
#define CONV_DIM  (D_INNER + 2 * D_STATE)          // 2304
#define D_IN_PROJ (2 * D_INNER + 2 * D_STATE + NHEADS) // 4384
#define N_PAD     4480                             // 35 * 128
#define BATCH     2
#define SEQLEN    2048
#define BL        (BATCH * SEQLEN)                 // 4096
#define EPS       1e-5f

#define NC    16
#define CHUNK 128

typedef __bf16 bf16x8 __attribute__((ext_vector_type(8)));
typedef float  f32x4  __attribute__((ext_vector_type(4)));
typedef unsigned short u16x8 __attribute__((ext_vector_type(8)));

__device__ __forceinline__ float siluf(float x) {
    return x / (1.0f + expf(-x));
}
__device__ __forceinline__ float softplusf(float x) {
    return (x > 20.0f) ? x : log1pf(expf(x));
}
__device__ __forceinline__ unsigned short f2bf(float f) {
    union { float f; unsigned u; } v; v.f = f;
    unsigned r = (v.u + 0x7FFFu + ((v.u >> 16) & 1u)) >> 16;  // RNE
    return (unsigned short)r;
}

// ---------------------------------------------------------------------------
// fp32 -> bf16 cast kernels
// ---------------------------------------------------------------------------
__global__ __launch_bounds__(256) void cast_bf16_kernel(
    const float* __restrict__ in, unsigned short* __restrict__ out, int n8)
{
    const int i = blockIdx.x * 256 + threadIdx.x;
    if (i >= n8) return;
    const float4* p = reinterpret_cast<const float4*>(in + (size_t)i * 8);
    float4 a = p[0], b = p[1];
    u16x8 o;
    o[0] = f2bf(a.x); o[1] = f2bf(a.y); o[2] = f2bf(a.z); o[3] = f2bf(a.w);
    o[4] = f2bf(b.x); o[5] = f2bf(b.y); o[6] = f2bf(b.z); o[7] = f2bf(b.w);
    *reinterpret_cast<u16x8*>(out + (size_t)i * 8) = o;
}

// W_in [4384][1024] -> bf16 padded [4480][1024] (zero rows >= 4384)
__global__ __launch_bounds__(256) void cast_win_kernel(
    const float* __restrict__ W, unsigned short* __restrict__ out)
{
    const int i = blockIdx.x * 256 + threadIdx.x;
    if (i >= N_PAD * D_MODEL / 8) return;
    const int row = i / (D_MODEL / 8);
    u16x8 o;
    if (row < D_IN_PROJ) {
        const float4* p = reinterpret_cast<const float4*>(W + (size_t)i * 8);
        float4 a = p[0], b = p[1];
        o[0] = f2bf(a.x); o[1] = f2bf(a.y); o[2] = f2bf(a.z); o[3] = f2bf(a.w);
        o[4] = f2bf(b.x); o[5] = f2bf(b.y); o[6] = f2bf(b.z); o[7] = f2bf(b.w);
    } else {
        o = (u16x8)(unsigned short)0;
    }
    *reinterpret_cast<u16x8*>(out + (size_t)i * 8) = o;
}

// ---------------------------------------------------------------------------
// bf16 MFMA GEMM (NT): C[m,n] = sum_k A[m,k]*B[n,k].  A:[M][K], B:[N][K] bf16,
// C fp32 [M][ldc].  128x128 tile, BK=32, 256 thr = 4 waves (2x2), each wave a
// 64x64 sub-tile = 4x4 frags of 16x16x32 MFMA.  global_load_lds(16B) staging
// into linear LDS; involutory XOR swizzle (o ^= ((o>>7)&7)<<4) applied to the
// GLOBAL source and to the ds_read address (both-sides, rule 21) -> 2-way
// conflicts only.  M%128==0; K%32==0; N guarded on C-store (B padded).
// ---------------------------------------------------------------------------
#define GBM 128
#define GBK 32

__device__ __forceinline__ unsigned swz(unsigned o) {
    return o ^ (((o >> 7) & 7u) << 4);
}

__device__ __forceinline__ void gld_lds16(const unsigned short* gsrc,
                                          unsigned short* lds) {
    auto* l = reinterpret_cast<__attribute__((address_space(3))) unsigned int*>(
        reinterpret_cast<uintptr_t>(lds));
    const auto* g =
        reinterpret_cast<const __attribute__((address_space(1))) unsigned int*>(
            reinterpret_cast<uintptr_t>(gsrc));
    __builtin_amdgcn_global_load_lds(g, l, 16, 0, 0);
}

__global__ __launch_bounds__(256) void gemm_bf16_nt(
    const unsigned short* __restrict__ A, const unsigned short* __restrict__ B,
    float* __restrict__ C, int M, int N, int K, int ldc)
{
    __shared__ unsigned short As[GBM * GBK];   // 8 KB
    __shared__ unsigned short Bs[GBM * GBK];   // 8 KB

    const int tid = threadIdx.x;
    const int bm = blockIdx.y * GBM;
    const int bn = blockIdx.x * GBM;

    // staging: per thread two 16B chunks per tile; LDS dest linear (d bytes),
    // global src at swizzled logical position swz(d).
    const unsigned d0 = tid * 16;
    const unsigned d1 = 4096 + tid * 16;
    const unsigned o0 = swz(d0), o1 = swz(d1);
    const int r0 = o0 >> 6, c0 = (o0 & 63) >> 1;
    const int r1 = o1 >> 6, c1 = (o1 & 63) >> 1;
    const unsigned short* a_src0 = A + (size_t)(bm + r0) * K + c0;
    const unsigned short* a_src1 = A + (size_t)(bm + r1) * K + c1;
    const unsigned short* b_src0 = B + (size_t)(bn + r0) * K + c0;
    const unsigned short* b_src1 = B + (size_t)(bn + r1) * K + c1;
    unsigned short* a_dst0 = As + (d0 >> 1);
    unsigned short* a_dst1 = As + (d1 >> 1);
    unsigned short* b_dst0 = Bs + (d0 >> 1);
    unsigned short* b_dst1 = Bs + (d1 >> 1);

    const int lane = tid & 63;
    const int wave = tid >> 6;
    const int wr = wave >> 1, wc = wave & 1;
    const int fr = lane & 15;          // frag row (m or n within 16)
    const int ko = (lane >> 4) * 8;    // k-offset within 32

    unsigned a_off[4], b_off[4];
    #pragma unroll
    for (int i = 0; i < 4; ++i) {
        a_off[i] = swz(((unsigned)(wr * 64 + i * 16 + fr) << 6) + ko * 2);
        b_off[i] = swz(((unsigned)(wc * 64 + i * 16 + fr) << 6) + ko * 2);
    }

    f32x4 acc[4][4] = {};

    for (int k0 = 0; k0 < K; k0 += GBK) {
        gld_lds16(a_src0, a_dst0);
        gld_lds16(a_src1, a_dst1);
        gld_lds16(b_src0, b_dst0);
        gld_lds16(b_src1, b_dst1);
        __syncthreads();   // drains vmcnt before barrier (compiler-inserted)

        bf16x8 af[4], bfr[4];
        #pragma unroll
        for (int i = 0; i < 4; ++i)
            af[i] = *reinterpret_cast<const bf16x8*>(
                reinterpret_cast<const char*>(As) + a_off[i]);
        #pragma unroll
        for (int j = 0; j < 4; ++j)
            bfr[j] = *reinterpret_cast<const bf16x8*>(
                reinterpret_cast<const char*>(Bs) + b_off[j]);
        #pragma unroll
        for (int i = 0; i < 4; ++i)
            #pragma unroll
            for (int j = 0; j < 4; ++j)
                acc[i][j] = __builtin_amdgcn_mfma_f32_16x16x32_bf16(
                    af[i], bfr[j], acc[i][j], 0, 0, 0);
        __syncthreads();
        a_src0 += GBK; a_src1 += GBK; b_src0 += GBK; b_src1 += GBK;
    }

    // C/D layout: col = lane&15, row = (lane>>4)*4 + reg   [m89-verified]
    const int mr = (lane >> 4) * 4;
    #pragma unroll
    for (int i = 0; i < 4; ++i) {
        const int gm = bm + wr * 64 + i * 16 + mr;
        #pragma unroll
        for (int j = 0; j < 4; ++j) {
            const int gn = bn + wc * 64 + j * 16 + fr;
            if (gn < N) {
                #pragma unroll
                for (int r = 0; r < 4; ++r)
                    C[(size_t)(gm + r) * ldc + gn] = acc[i][j][r];
            }
        }
    }
}

// ---------------------------------------------------------------------------
// Causal depthwise conv (K=4) + SiLU over the xBC slice of zxbcdt.
// ---------------------------------------------------------------------------
__global__ __launch_bounds__(256) void conv_silu_kernel(
    const float* __restrict__ zxbcdt, const float* __restrict__ conv_w,
    const float* __restrict__ conv_b, float* __restrict__ xbc_out)
{
    const int idx = blockIdx.x * 256 + threadIdx.x;
    if (idx >= BL * CONV_DIM) return;
    const int c  = idx % CONV_DIM;
    const int bl = idx / CONV_DIM;
    const int l  = bl % SEQLEN;
    const int b  = bl / SEQLEN;

    float acc = conv_b[c];
    #pragma unroll
    for (int k = 0; k < D_CONV; ++k) {
        const int ll = l + k - (D_CONV - 1);
        if (ll >= 0) {
            acc += zxbcdt[(size_t)(b * SEQLEN + ll) * D_IN_PROJ + D_INNER + c]
                   * conv_w[c * D_CONV + k];
        }
    }
    xbc_out[idx] = siluf(acc);
}

// ---------------------------------------------------------------------------
// dt = softplus(dt_raw + dt_bias)
// ---------------------------------------------------------------------------
__global__ __launch_bounds__(256) void dt_kernel(
    const float* __restrict__ zxbcdt, const float* __restrict__ dt_bias,
    float* __restrict__ dt_out)
{
    const int idx = blockIdx.x * 256 + threadIdx.x;
    if (idx >= BL * NHEADS) return;
    const int h  = idx % NHEADS;
    const int bl = idx / NHEADS;
    const float v = zxbcdt[(size_t)bl * D_IN_PROJ + D_INNER + CONV_DIM + h]
                    + dt_bias[h];
    dt_out[idx] = softplusf(v);
}

// ---------------------------------------------------------------------------
// Chunked SSD scan (3 phases) — unchanged (verified Round 4).
// ---------------------------------------------------------------------------
struct LBa { float4 b0, b1; float x, d; };

__device__ __forceinline__ void load_a(LBa& L, const float* __restrict__ row,
                                       int xoff, int n0,
                                       const float* __restrict__ dtp, int t) {
    L.b0 = *reinterpret_cast<const float4*>(&row[D_INNER + n0]);
    L.b1 = *reinterpret_cast<const float4*>(&row[D_INNER + n0 + 4]);
    L.x  = row[xoff];
    L.d  = dtp[(size_t)t * NHEADS];
}

__device__ __forceinline__ void step_a(float (&hs)[8], const LBa& L,
                                       float A_h, float& sdt) {
    sdt += L.d;
    const float dA  = __expf(A_h * L.d);
    const float dtx = L.d * L.x;
    hs[0] = hs[0] * dA + dtx * L.b0.x;
    hs[1] = hs[1] * dA + dtx * L.b0.y;
    hs[2] = hs[2] * dA + dtx * L.b0.z;
    hs[3] = hs[3] * dA + dtx * L.b0.w;
    hs[4] = hs[4] * dA + dtx * L.b1.x;
    hs[5] = hs[5] * dA + dtx * L.b1.y;
    hs[6] = hs[6] * dA + dtx * L.b1.z;
    hs[7] = hs[7] * dA + dtx * L.b1.w;
}

__global__ __launch_bounds__(256) void ssd_chunk_state(
    const float* __restrict__ xbc, const float* __restrict__ dt,
    const float* __restrict__ A_log,
    float* __restrict__ S, float* __restrict__ alpha)
{
    const int bid = blockIdx.x;
    const int pq = bid & 3;
    const int h  = (bid >> 2) & 31;
    const int b  = (bid >> 7) & 1;
    const int c  = bid >> 8;
    const int tid = threadIdx.x;
    const int pl = tid >> 4;
    const int n0 = (tid & 15) * 8;
    const int xoff = h * HEADDIM + pq * 16 + pl;

    const float A_h = -__expf(A_log[h]);
    const float* xb  = xbc + (size_t)(b * SEQLEN + c * CHUNK) * CONV_DIM;
    const float* dtp = dt  + (size_t)(b * SEQLEN + c * CHUNK) * NHEADS + h;

    float hs[8] = {};
    float sdt = 0.f;
    LBa La, Lb;
    load_a(La, xb, xoff, n0, dtp, 0);
    for (int t = 0; t < CHUNK; t += 2) {
        load_a(Lb, xb + (size_t)(t + 1) * CONV_DIM, xoff, n0, dtp, t + 1);
        step_a(hs, La, A_h, sdt);
        if (t + 2 < CHUNK)
            load_a(La, xb + (size_t)(t + 2) * CONV_DIM, xoff, n0, dtp, t + 2);
        step_a(hs, Lb, A_h, sdt);
    }
    float* Sp = S + (size_t)bid * 2048 + tid * 8;
    *reinterpret_cast<float4*>(Sp)     = make_float4(hs[0], hs[1], hs[2], hs[3]);
    *reinterpret_cast<float4*>(Sp + 4) = make_float4(hs[4], hs[5], hs[6], hs[7]);
    if (tid == 0 && pq == 0) alpha[(c * 2 + b) * 32 + h] = __expf(A_h * sdt);
}

__global__ __launch_bounds__(256) void ssd_state_scan(
    float* __restrict__ S, const float* __restrict__ alpha)
{
    const int bid = blockIdx.x;       // (b,h,pq)
    const int pq = bid & 3;
    const int h  = (bid >> 2) & 31;
    const int b  = bid >> 7;
    const int tid = threadIdx.x;
    float h0[8] = {};
    #pragma unroll 2
    for (int c = 0; c < NC; ++c) {
        const int sb = ((c * 2 + b) * 32 + h) * 4 + pq;
        float* Sp = S + (size_t)sb * 2048 + tid * 8;
        const float al = alpha[(c * 2 + b) * 32 + h];
        float4 t0 = *reinterpret_cast<const float4*>(Sp);
        float4 t1 = *reinterpret_cast<const float4*>(Sp + 4);
        *reinterpret_cast<float4*>(Sp)     = make_float4(h0[0], h0[1], h0[2], h0[3]);
        *reinterpret_cast<float4*>(Sp + 4) = make_float4(h0[4], h0[5], h0[6], h0[7]);
        h0[0] = h0[0] * al + t0.x;
        h0[1] = h0[1] * al + t0.y;
        h0[2] = h0[2] * al + t0.z;
        h0[3] = h0[3] * al + t0.w;
        h0[4] = h0[4] * al + t1.x;
        h0[5] = h0[5] * al + t1.y;
        h0[6] = h0[6] * al + t1.z;
        h0[7] = h0[7] * al + t1.w;
    }
}

struct LBc { float4 b0, b1, c0, c1; float x, d; };

__device__ __forceinline__ void load_c(LBc& L, const float* __restrict__ row,
                                       int xoff, int n0,
                                       const float* __restrict__ dtp, int t) {
    L.b0 = *reinterpret_cast<const float4*>(&row[D_INNER + n0]);
    L.b1 = *reinterpret_cast<const float4*>(&row[D_INNER + n0 + 4]);
    L.c0 = *reinterpret_cast<const float4*>(&row[D_INNER + D_STATE + n0]);
    L.c1 = *reinterpret_cast<const float4*>(&row[D_INNER + D_STATE + n0 + 4]);
    L.x  = row[xoff];
    L.d  = dtp[(size_t)t * NHEADS];
}

__device__ __forceinline__ float step_c(float (&hs)[8], const LBc& L, float A_h) {
    const float dA  = __expf(A_h * L.d);
    const float dtx = L.d * L.x;
    float acc;
    hs[0] = hs[0] * dA + dtx * L.b0.x;  acc  = hs[0] * L.c0.x;
    hs[1] = hs[1] * dA + dtx * L.b0.y;  acc += hs[1] * L.c0.y;
    hs[2] = hs[2] * dA + dtx * L.b0.z;  acc += hs[2] * L.c0.z;
    hs[3] = hs[3] * dA + dtx * L.b0.w;  acc += hs[3] * L.c0.w;
    hs[4] = hs[4] * dA + dtx * L.b1.x;  acc += hs[4] * L.c1.x;
    hs[5] = hs[5] * dA + dtx * L.b1.y;  acc += hs[5] * L.c1.y;
    hs[6] = hs[6] * dA + dtx * L.b1.z;  acc += hs[6] * L.c1.z;
    hs[7] = hs[7] * dA + dtx * L.b1.w;  acc += hs[7] * L.c1.w;
    return acc;
}

__global__ __launch_bounds__(256) void ssd_chunk_out(
    const float* __restrict__ xbc, const float* __restrict__ dt,
    const float* __restrict__ A_log, const float* __restrict__ Dp,
    const float* __restrict__ S, float* __restrict__ y)
{
    const int bid = blockIdx.x;
    const int pq = bid & 3;
    const int h  = (bid >> 2) & 31;
    const int b  = (bid >> 7) & 1;
    const int c  = bid >> 8;
    const int tid = threadIdx.x;
    const int pl = tid >> 4;
    const int n0 = (tid & 15) * 8;
    const int xoff = h * HEADDIM + pq * 16 + pl;

    const float A_h = -__expf(A_log[h]);
    const float D_h = Dp[h];
    const float* xb  = xbc + (size_t)(b * SEQLEN + c * CHUNK) * CONV_DIM;
    const float* dtp = dt  + (size_t)(b * SEQLEN + c * CHUNK) * NHEADS + h;
    float* yb = y + (size_t)(b * SEQLEN + c * CHUNK) * D_INNER + xoff;

    float hs[8];
    const float* Hp = S + (size_t)bid * 2048 + tid * 8;
    {
        float4 h0 = *reinterpret_cast<const float4*>(Hp);
        float4 h1 = *reinterpret_cast<const float4*>(Hp + 4);
        hs[0] = h0.x; hs[1] = h0.y; hs[2] = h0.z; hs[3] = h0.w;
        hs[4] = h1.x; hs[5] = h1.y; hs[6] = h1.z; hs[7] = h1.w;
    }

    LBc La, Lb;
    load_c(La, xb, xoff, n0, dtp, 0);
    for (int t = 0; t < CHUNK; t += 2) {
        load_c(Lb, xb + (size_t)(t + 1) * CONV_DIM, xoff, n0, dtp, t + 1);
        float acc = step_c(hs, La, A_h);
        acc += __shfl_xor(acc, 1, 64);
        acc += __shfl_xor(acc, 2, 64);
        acc += __shfl_xor(acc, 4, 64);
        acc += __shfl_xor(acc, 8, 64);
        if ((tid & 15) == 0) yb[(size_t)t * D_INNER] = acc + D_h * La.x;
        if (t + 2 < CHUNK)
            load_c(La, xb + (size_t)(t + 2) * CONV_DIM, xoff, n0, dtp, t + 2);
        float acc2 = step_c(hs, Lb, A_h);
        acc2 += __shfl_xor(acc2, 1, 64);
        acc2 += __shfl_xor(acc2, 2, 64);
        acc2 += __shfl_xor(acc2, 4, 64);
        acc2 += __shfl_xor(acc2, 8, 64);
        if ((tid & 15) == 0) yb[(size_t)(t + 1) * D_INNER] = acc2 + D_h * Lb.x;
    }
}

// ---------------------------------------------------------------------------
// yg = y * silu(z); rmsnorm(yg) * norm_w -> bf16 output (feeds GEMM2).
// ---------------------------------------------------------------------------
__global__ __launch_bounds__(256) void gate_norm_kernel(
    const float* __restrict__ y,
    const float* __restrict__ zxbcdt,
    const float* __restrict__ norm_w,
    unsigned short* __restrict__ ybf)
{
    const int row = blockIdx.x;
    const int tid = threadIdx.x;
    const float* yr = y + (size_t)row * D_INNER;
    const float* zr = zxbcdt + (size_t)row * D_IN_PROJ;

    float v[8];
    float ss = 0.f;
    #pragma unroll
    for (int j = 0; j < 2; ++j) {
        float4 y4 = *reinterpret_cast<const float4*>(&yr[tid * 8 + j * 4]);
        float4 z4 = *reinterpret_cast<const float4*>(&zr[tid * 8 + j * 4]);
        float a0 = y4.x * siluf(z4.x);
        float a1 = y4.y * siluf(z4.y);
        float a2 = y4.z * siluf(z4.z);
        float a3 = y4.w * siluf(z4.w);
        v[j * 4 + 0] = a0; v[j * 4 + 1] = a1;
        v[j * 4 + 2] = a2; v[j * 4 + 3] = a3;
        ss += a0 * a0 + a1 * a1 + a2 * a2 + a3 * a3;
    }
    #pragma unroll
    for (int o = 1; o < 64; o <<= 1) ss += __shfl_xor(ss, o, 64);
    __shared__ float red[4];
    if ((tid & 63) == 0) red[tid >> 6] = ss;
    __syncthreads();
    const float tot = red[0] + red[1] + red[2] + red[3];
    const float rs = rsqrtf(tot * (1.0f / D_INNER) + EPS);

    const float4* nw = reinterpret_cast<const float4*>(&norm_w[tid * 8]);
    float4 w0 = nw[0], w1 = nw[1];
    u16x8 o;
    o[0] = f2bf(v[0] * rs * w0.x);
    o[1] = f2bf(v[1] * rs * w0.y);
    o[2] = f2bf(v[2] * rs * w0.z);
    o[3] = f2bf(v[3] * rs * w0.w);
    o[4] = f2bf(v[4] * rs * w1.x);
    o[5] = f2bf(v[5] * rs * w1.y);
    o[6] = f2bf(v[6] * rs * w1.z);
    o[7] = f2bf(v[7] * rs * w1.w);
    *reinterpret_cast<u16x8*>(&ybf[(size_t)row * D_INNER + tid * 8]) = o;
}

// ---------------------------------------------------------------------------
extern "C" void kernel_launch(void* const* d_in, const int* in_sizes, int n_in,
                              void* d_out, int out_size, void* d_ws, size_t ws_size,
                              hipStream_t stream)
{
    const float* u       = (const float*)d_in[0];
    const float* W_in    = (const float*)d_in[1];
    const float* conv_w  = (const float*)d_in[2];
    const float* conv_b  = (const float*)d_in[3];
    const float* dt_bias = (const float*)d_in[4];
    const float* A_log   = (const float*)d_in[5];
    const float* Dp      = (const float*)d_in[6];
    const float* norm_w  = (const float*)d_in[7];
    const float* W_out   = (const float*)d_in[8];
    float* out = (float*)d_out;

    float* zxbcdt = (float*)d_ws;                          // 4096*4384 f32
    float* xbc    = zxbcdt + (size_t)BL * D_IN_PROJ;       // 4096*2304 f32
    float* dt_sp  = xbc    + (size_t)BL * CONV_DIM;        // 4096*32 f32
    float* yb     = dt_sp  + (size_t)BL * NHEADS;          // 4096*2048 f32
    float* Sbuf   = yb     + (size_t)BL * D_INNER;         // 8,388,608 f32
    float* alphab = Sbuf   + (size_t)NC * BATCH * NHEADS * HEADDIM * D_STATE;

    // bf16 buffers alias Sbuf across its dead phases:
    //   pre-GEMM1:  ubf [4096*1024], wibf [4480*1024]   (dead once scan starts)
    //   post-scan:  ybbf [4096*2048], wobf [1024*2048]
    unsigned short* ubf  = (unsigned short*)Sbuf;
    unsigned short* wibf = (unsigned short*)Sbuf + (size_t)BL * D_MODEL;
    unsigned short* ybbf = (unsigned short*)Sbuf;
    unsigned short* wobf = (unsigned short*)Sbuf + (size_t)BL * D_INNER;

    // 0. casts for GEMM1
    cast_bf16_kernel<<<(BL * D_MODEL / 8 + 255) / 256, 256, 0, stream>>>(
        u, ubf, BL * D_MODEL / 8);
    cast_win_kernel<<<(N_PAD * D_MODEL / 8 + 255) / 256, 256, 0, stream>>>(
        W_in, wibf);
    // 1. in-projection GEMM (bf16 MFMA): zxbcdt = u @ W_in^T
    {
        dim3 grid(N_PAD / GBM, BL / GBM);
        gemm_bf16_nt<<<grid, 256, 0, stream>>>(
            ubf, wibf, zxbcdt, BL, D_IN_PROJ, D_MODEL, D_IN_PROJ);
    }
    // 2. causal depthwise conv + SiLU
    {
        const int n = BL * CONV_DIM;
        conv_silu_kernel<<<(n + 255) / 256, 256, 0, stream>>>(
            zxbcdt, conv_w, conv_b, xbc);
    }
    // 3. dt = softplus(dt_raw + bias)
    {
        const int n = BL * NHEADS;
        dt_kernel<<<(n + 255) / 256, 256, 0, stream>>>(zxbcdt, dt_bias, dt_sp);
    }
    // 4. chunked SSD scan
    ssd_chunk_state<<<NC * BATCH * NHEADS * 4, 256, 0, stream>>>(
        xbc, dt_sp, A_log, Sbuf, alphab);
    ssd_state_scan<<<BATCH * NHEADS * 4, 256, 0, stream>>>(Sbuf, alphab);
    ssd_chunk_out<<<NC * BATCH * NHEADS * 4, 256, 0, stream>>>(
        xbc, dt_sp, A_log, Dp, Sbuf, yb);
    // 5. cast W_out (aliases Sbuf tail — must follow ssd_chunk_out)
    cast_bf16_kernel<<<(D_MODEL * D_INNER / 8 + 255) / 256, 256, 0, stream>>>(
        W_out, wobf, D_MODEL * D_INNER / 8);
    // 6. gate + RMSNorm -> bf16
    gate_norm_kernel<<<BL, 256, 0, stream>>>(yb, zxbcdt, norm_w, ybbf);
    // 7. out-projection GEMM (bf16 MFMA): out = ybg @ W_out^T
    {
        dim3 grid(D_MODEL / GBM, BL / GBM);
        gemm_bf16_nt<<<grid, 256, 0, stream>>>(
            ybbf, wobf, out, BL, D_MODEL, D_INNER, D_MODEL);
    }
}

// Round 7
// 494.635 us; speedup vs baseline: 5.9511x; 1.4247x over previous
//
#include <hip/hip_runtime.h>
#include <hip/hip_bf16.h>
#include <math.h>
#include <stdint.h>

#define D_MODEL   1024
#define D_INNER   2048
#define HEADDIM   64
#define NHEADS    32
#define D_STATE   128
#define D_CONV    4
#define CONV_DIM  (D_INNER + 2 * D_STATE)          // 2304
#define D_IN_PROJ (2 * D_INNER + 2 * D_STATE + NHEADS) // 4384
#define N_PAD     4480                             // 35 * 128
#define BATCH     2
#define SEQLEN    2048
#define BL        (BATCH * SEQLEN)                 // 4096
#define EPS       1e-5f

#define NC    16
#define CHUNK 128

typedef __bf16 bf16x8 __attribute__((ext_vector_type(8)));
typedef float  f32x4  __attribute__((ext_vector_type(4)));
typedef unsigned short u16x8 __attribute__((ext_vector_type(8)));

__device__ __forceinline__ float siluf(float x) {
    return x / (1.0f + expf(-x));
}
__device__ __forceinline__ float softplusf(float x) {
    return (x > 20.0f) ? x : log1pf(expf(x));
}
__device__ __forceinline__ unsigned short f2bf(float f) {
    union { float f; unsigned u; } v; v.f = f;
    unsigned r = (v.u + 0x7FFFu + ((v.u >> 16) & 1u)) >> 16;  // RNE
    return (unsigned short)r;
}

// ---------------------------------------------------------------------------
// fp32 -> bf16 cast kernels
// ---------------------------------------------------------------------------
__global__ __launch_bounds__(256) void cast_bf16_kernel(
    const float* __restrict__ in, unsigned short* __restrict__ out, int n8)
{
    const int i = blockIdx.x * 256 + threadIdx.x;
    if (i >= n8) return;
    const float4* p = reinterpret_cast<const float4*>(in + (size_t)i * 8);
    float4 a = p[0], b = p[1];
    u16x8 o;
    o[0] = f2bf(a.x); o[1] = f2bf(a.y); o[2] = f2bf(a.z); o[3] = f2bf(a.w);
    o[4] = f2bf(b.x); o[5] = f2bf(b.y); o[6] = f2bf(b.z); o[7] = f2bf(b.w);
    *reinterpret_cast<u16x8*>(out + (size_t)i * 8) = o;
}

// W_in [4384][1024] -> bf16 padded [4480][1024] (zero rows >= 4384)
__global__ __launch_bounds__(256) void cast_win_kernel(
    const float* __restrict__ W, unsigned short* __restrict__ out)
{
    const int i = blockIdx.x * 256 + threadIdx.x;
    if (i >= N_PAD * D_MODEL / 8) return;
    const int row = i / (D_MODEL / 8);
    u16x8 o;
    if (row < D_IN_PROJ) {
        const float4* p = reinterpret_cast<const float4*>(W + (size_t)i * 8);
        float4 a = p[0], b = p[1];
        o[0] = f2bf(a.x); o[1] = f2bf(a.y); o[2] = f2bf(a.z); o[3] = f2bf(a.w);
        o[4] = f2bf(b.x); o[5] = f2bf(b.y); o[6] = f2bf(b.z); o[7] = f2bf(b.w);
    } else {
        o = (u16x8)(unsigned short)0;
    }
    *reinterpret_cast<u16x8*>(out + (size_t)i * 8) = o;
}

// ---------------------------------------------------------------------------
// bf16 MFMA GEMM (NT) — unchanged (verified Round 6).
// ---------------------------------------------------------------------------
#define GBM 128
#define GBK 32

__device__ __forceinline__ unsigned swz(unsigned o) {
    return o ^ (((o >> 7) & 7u) << 4);
}

__device__ __forceinline__ void gld_lds16(const unsigned short* gsrc,
                                          unsigned short* lds) {
    auto* l = reinterpret_cast<__attribute__((address_space(3))) unsigned int*>(
        reinterpret_cast<uintptr_t>(lds));
    const auto* g =
        reinterpret_cast<const __attribute__((address_space(1))) unsigned int*>(
            reinterpret_cast<uintptr_t>(gsrc));
    __builtin_amdgcn_global_load_lds(g, l, 16, 0, 0);
}

__global__ __launch_bounds__(256) void gemm_bf16_nt(
    const unsigned short* __restrict__ A, const unsigned short* __restrict__ B,
    float* __restrict__ C, int M, int N, int K, int ldc)
{
    __shared__ unsigned short As[GBM * GBK];   // 8 KB
    __shared__ unsigned short Bs[GBM * GBK];   // 8 KB

    const int tid = threadIdx.x;
    const int bm = blockIdx.y * GBM;
    const int bn = blockIdx.x * GBM;

    const unsigned d0 = tid * 16;
    const unsigned d1 = 4096 + tid * 16;
    const unsigned o0 = swz(d0), o1 = swz(d1);
    const int r0 = o0 >> 6, c0 = (o0 & 63) >> 1;
    const int r1 = o1 >> 6, c1 = (o1 & 63) >> 1;
    const unsigned short* a_src0 = A + (size_t)(bm + r0) * K + c0;
    const unsigned short* a_src1 = A + (size_t)(bm + r1) * K + c1;
    const unsigned short* b_src0 = B + (size_t)(bn + r0) * K + c0;
    const unsigned short* b_src1 = B + (size_t)(bn + r1) * K + c1;
    unsigned short* a_dst0 = As + (d0 >> 1);
    unsigned short* a_dst1 = As + (d1 >> 1);
    unsigned short* b_dst0 = Bs + (d0 >> 1);
    unsigned short* b_dst1 = Bs + (d1 >> 1);

    const int lane = tid & 63;
    const int wave = tid >> 6;
    const int wr = wave >> 1, wc = wave & 1;
    const int fr = lane & 15;
    const int ko = (lane >> 4) * 8;

    unsigned a_off[4], b_off[4];
    #pragma unroll
    for (int i = 0; i < 4; ++i) {
        a_off[i] = swz(((unsigned)(wr * 64 + i * 16 + fr) << 6) + ko * 2);
        b_off[i] = swz(((unsigned)(wc * 64 + i * 16 + fr) << 6) + ko * 2);
    }

    f32x4 acc[4][4] = {};

    for (int k0 = 0; k0 < K; k0 += GBK) {
        gld_lds16(a_src0, a_dst0);
        gld_lds16(a_src1, a_dst1);
        gld_lds16(b_src0, b_dst0);
        gld_lds16(b_src1, b_dst1);
        __syncthreads();

        bf16x8 af[4], bfr[4];
        #pragma unroll
        for (int i = 0; i < 4; ++i)
            af[i] = *reinterpret_cast<const bf16x8*>(
                reinterpret_cast<const char*>(As) + a_off[i]);
        #pragma unroll
        for (int j = 0; j < 4; ++j)
            bfr[j] = *reinterpret_cast<const bf16x8*>(
                reinterpret_cast<const char*>(Bs) + b_off[j]);
        #pragma unroll
        for (int i = 0; i < 4; ++i)
            #pragma unroll
            for (int j = 0; j < 4; ++j)
                acc[i][j] = __builtin_amdgcn_mfma_f32_16x16x32_bf16(
                    af[i], bfr[j], acc[i][j], 0, 0, 0);
        __syncthreads();
        a_src0 += GBK; a_src1 += GBK; b_src0 += GBK; b_src1 += GBK;
    }

    const int mr = (lane >> 4) * 4;
    #pragma unroll
    for (int i = 0; i < 4; ++i) {
        const int gm = bm + wr * 64 + i * 16 + mr;
        #pragma unroll
        for (int j = 0; j < 4; ++j) {
            const int gn = bn + wc * 64 + j * 16 + fr;
            if (gn < N) {
                #pragma unroll
                for (int r = 0; r < 4; ++r)
                    C[(size_t)(gm + r) * ldc + gn] = acc[i][j][r];
            }
        }
    }
}

// ---------------------------------------------------------------------------
// Causal depthwise conv (K=4) + SiLU over the xBC slice of zxbcdt.
// ---------------------------------------------------------------------------
__global__ __launch_bounds__(256) void conv_silu_kernel(
    const float* __restrict__ zxbcdt, const float* __restrict__ conv_w,
    const float* __restrict__ conv_b, float* __restrict__ xbc_out)
{
    const int idx = blockIdx.x * 256 + threadIdx.x;
    if (idx >= BL * CONV_DIM) return;
    const int c  = idx % CONV_DIM;
    const int bl = idx / CONV_DIM;
    const int l  = bl % SEQLEN;
    const int b  = bl / SEQLEN;

    float acc = conv_b[c];
    #pragma unroll
    for (int k = 0; k < D_CONV; ++k) {
        const int ll = l + k - (D_CONV - 1);
        if (ll >= 0) {
            acc += zxbcdt[(size_t)(b * SEQLEN + ll) * D_IN_PROJ + D_INNER + c]
                   * conv_w[c * D_CONV + k];
        }
    }
    xbc_out[idx] = siluf(acc);
}

// ---------------------------------------------------------------------------
// dt = softplus(dt_raw + dt_bias)
// ---------------------------------------------------------------------------
__global__ __launch_bounds__(256) void dt_kernel(
    const float* __restrict__ zxbcdt, const float* __restrict__ dt_bias,
    float* __restrict__ dt_out)
{
    const int idx = blockIdx.x * 256 + threadIdx.x;
    if (idx >= BL * NHEADS) return;
    const int h  = idx % NHEADS;
    const int bl = idx / NHEADS;
    const float v = zxbcdt[(size_t)bl * D_IN_PROJ + D_INNER + CONV_DIM + h]
                    + dt_bias[h];
    dt_out[idx] = softplusf(v);
}

// ---------------------------------------------------------------------------
// Chunked SSD scan, 4p x 8n per-thread state blocks (32 states/thread).
// Grid (chunk kernels): NC*BATCH*NHEADS = 1024 blocks, 256 threads.
//   thread: pp = tid>>4 -> p in [pp*4, pp*4+4);  nc = tid&15 -> n in [nc*8,+8)
// S layout: S[cbh][p][n], cbh = (c*2+b)*32+h, 8192 floats per (c,b,h).
// Loads per step: B 2xfloat4 (+C 2xfloat4 in out-phase), x 1xfloat4, dt scalar
// -> feeds 32 (64) FMA: ~3.4x fewer L1 bytes/state than the 8-state layout.
// ---------------------------------------------------------------------------
struct LSa { float4 b0, b1, x4; float d; };

__device__ __forceinline__ void load_sa(LSa& L, const float* __restrict__ row,
                                        int xoff, int n0,
                                        const float* __restrict__ dtp, int t) {
    L.b0 = *reinterpret_cast<const float4*>(&row[D_INNER + n0]);
    L.b1 = *reinterpret_cast<const float4*>(&row[D_INNER + n0 + 4]);
    L.x4 = *reinterpret_cast<const float4*>(&row[xoff]);
    L.d  = dtp[(size_t)t * NHEADS];
}

__device__ __forceinline__ void step_sa(float (&hs)[4][8], const LSa& L,
                                        float A_h, float& sdt) {
    sdt += L.d;
    const float dA = __expf(A_h * L.d);
    const float B[8] = {L.b0.x, L.b0.y, L.b0.z, L.b0.w,
                        L.b1.x, L.b1.y, L.b1.z, L.b1.w};
    const float dtx[4] = {L.d * L.x4.x, L.d * L.x4.y, L.d * L.x4.z, L.d * L.x4.w};
    #pragma unroll
    for (int i = 0; i < 4; ++i)
        #pragma unroll
        for (int j = 0; j < 8; ++j)
            hs[i][j] = hs[i][j] * dA + dtx[i] * B[j];
}

__global__ __launch_bounds__(256) void ssd_chunk_state(
    const float* __restrict__ xbc, const float* __restrict__ dt,
    const float* __restrict__ A_log,
    float* __restrict__ S, float* __restrict__ alpha)
{
    const int bid = blockIdx.x;
    const int h = bid & 31;
    const int b = (bid >> 5) & 1;
    const int c = bid >> 6;
    const int tid = threadIdx.x;
    const int pp = tid >> 4;
    const int nc = tid & 15;
    const int n0 = nc * 8;
    const int xoff = h * HEADDIM + pp * 4;

    const float A_h = -__expf(A_log[h]);
    const float* xb  = xbc + (size_t)(b * SEQLEN + c * CHUNK) * CONV_DIM;
    const float* dtp = dt  + (size_t)(b * SEQLEN + c * CHUNK) * NHEADS + h;

    float hs[4][8] = {};
    float sdt = 0.f;
    LSa La, Lb;
    load_sa(La, xb, xoff, n0, dtp, 0);
    for (int t = 0; t < CHUNK; t += 2) {
        load_sa(Lb, xb + (size_t)(t + 1) * CONV_DIM, xoff, n0, dtp, t + 1);
        step_sa(hs, La, A_h, sdt);
        if (t + 2 < CHUNK)
            load_sa(La, xb + (size_t)(t + 2) * CONV_DIM, xoff, n0, dtp, t + 2);
        step_sa(hs, Lb, A_h, sdt);
    }
    const int cbh = (c * 2 + b) * 32 + h;
    float* Sp = S + (size_t)cbh * 8192 + (size_t)(pp * 4) * 128 + n0;
    #pragma unroll
    for (int i = 0; i < 4; ++i) {
        *reinterpret_cast<float4*>(Sp + i * 128) =
            make_float4(hs[i][0], hs[i][1], hs[i][2], hs[i][3]);
        *reinterpret_cast<float4*>(Sp + i * 128 + 4) =
            make_float4(hs[i][4], hs[i][5], hs[i][6], hs[i][7]);
    }
    if (tid == 0) alpha[cbh] = __expf(A_h * sdt);
}

__global__ __launch_bounds__(256) void ssd_state_scan(
    float* __restrict__ S, const float* __restrict__ alpha)
{
    const int bid = blockIdx.x;       // (b,h,q): q = p-quarter
    const int q = bid & 3;
    const int h = (bid >> 2) & 31;
    const int b = bid >> 7;
    const int tid = threadIdx.x;
    const size_t off = (size_t)(q * 16 + (tid >> 4)) * 128 + (tid & 15) * 8;
    float h0[8] = {};
    #pragma unroll 2
    for (int c = 0; c < NC; ++c) {
        const int cbh = (c * 2 + b) * 32 + h;
        float* Sp = S + (size_t)cbh * 8192 + off;
        const float al = alpha[cbh];
        float4 t0 = *reinterpret_cast<const float4*>(Sp);
        float4 t1 = *reinterpret_cast<const float4*>(Sp + 4);
        *reinterpret_cast<float4*>(Sp)     = make_float4(h0[0], h0[1], h0[2], h0[3]);
        *reinterpret_cast<float4*>(Sp + 4) = make_float4(h0[4], h0[5], h0[6], h0[7]);
        h0[0] = h0[0] * al + t0.x;
        h0[1] = h0[1] * al + t0.y;
        h0[2] = h0[2] * al + t0.z;
        h0[3] = h0[3] * al + t0.w;
        h0[4] = h0[4] * al + t1.x;
        h0[5] = h0[5] * al + t1.y;
        h0[6] = h0[6] * al + t1.z;
        h0[7] = h0[7] * al + t1.w;
    }
}

struct LSc { float4 b0, b1, c0, c1, x4; float d; };

__device__ __forceinline__ void load_sc(LSc& L, const float* __restrict__ row,
                                        int xoff, int n0,
                                        const float* __restrict__ dtp, int t) {
    L.b0 = *reinterpret_cast<const float4*>(&row[D_INNER + n0]);
    L.b1 = *reinterpret_cast<const float4*>(&row[D_INNER + n0 + 4]);
    L.c0 = *reinterpret_cast<const float4*>(&row[D_INNER + D_STATE + n0]);
    L.c1 = *reinterpret_cast<const float4*>(&row[D_INNER + D_STATE + n0 + 4]);
    L.x4 = *reinterpret_cast<const float4*>(&row[xoff]);
    L.d  = dtp[(size_t)t * NHEADS];
}

__device__ __forceinline__ void step_sc(float (&hs)[4][8], const LSc& L,
                                        float A_h, float (&acc)[4]) {
    const float dA = __expf(A_h * L.d);
    const float B[8] = {L.b0.x, L.b0.y, L.b0.z, L.b0.w,
                        L.b1.x, L.b1.y, L.b1.z, L.b1.w};
    const float C[8] = {L.c0.x, L.c0.y, L.c0.z, L.c0.w,
                        L.c1.x, L.c1.y, L.c1.z, L.c1.w};
    const float dtx[4] = {L.d * L.x4.x, L.d * L.x4.y, L.d * L.x4.z, L.d * L.x4.w};
    #pragma unroll
    for (int i = 0; i < 4; ++i) {
        float a = 0.f;
        #pragma unroll
        for (int j = 0; j < 8; ++j) {
            hs[i][j] = hs[i][j] * dA + dtx[i] * B[j];
            a += hs[i][j] * C[j];
        }
        acc[i] = a;
    }
}

__device__ __forceinline__ void reduce_store(float (&acc)[4], const LSc& L,
                                             float D_h, int nc, float* dst) {
    #pragma unroll
    for (int i = 0; i < 4; ++i) {
        acc[i] += __shfl_xor(acc[i], 1, 64);
        acc[i] += __shfl_xor(acc[i], 2, 64);
        acc[i] += __shfl_xor(acc[i], 4, 64);
        acc[i] += __shfl_xor(acc[i], 8, 64);
    }
    if (nc == 0) {
        float4 o;
        o.x = acc[0] + D_h * L.x4.x;
        o.y = acc[1] + D_h * L.x4.y;
        o.z = acc[2] + D_h * L.x4.z;
        o.w = acc[3] + D_h * L.x4.w;
        *reinterpret_cast<float4*>(dst) = o;
    }
}

__global__ __launch_bounds__(256) void ssd_chunk_out(
    const float* __restrict__ xbc, const float* __restrict__ dt,
    const float* __restrict__ A_log, const float* __restrict__ Dp,
    const float* __restrict__ S, float* __restrict__ y)
{
    const int bid = blockIdx.x;
    const int h = bid & 31;
    const int b = (bid >> 5) & 1;
    const int c = bid >> 6;
    const int tid = threadIdx.x;
    const int pp = tid >> 4;
    const int nc = tid & 15;
    const int n0 = nc * 8;
    const int xoff = h * HEADDIM + pp * 4;

    const float A_h = -__expf(A_log[h]);
    const float D_h = Dp[h];
    const float* xb  = xbc + (size_t)(b * SEQLEN + c * CHUNK) * CONV_DIM;
    const float* dtp = dt  + (size_t)(b * SEQLEN + c * CHUNK) * NHEADS + h;
    float* yb = y + (size_t)(b * SEQLEN + c * CHUNK) * D_INNER + xoff;

    const int cbh = (c * 2 + b) * 32 + h;
    float hs[4][8];
    {
        const float* Hp = S + (size_t)cbh * 8192 + (size_t)(pp * 4) * 128 + n0;
        #pragma unroll
        for (int i = 0; i < 4; ++i) {
            float4 h0 = *reinterpret_cast<const float4*>(Hp + i * 128);
            float4 h1 = *reinterpret_cast<const float4*>(Hp + i * 128 + 4);
            hs[i][0] = h0.x; hs[i][1] = h0.y; hs[i][2] = h0.z; hs[i][3] = h0.w;
            hs[i][4] = h1.x; hs[i][5] = h1.y; hs[i][6] = h1.z; hs[i][7] = h1.w;
        }
    }

    LSc La, Lb;
    load_sc(La, xb, xoff, n0, dtp, 0);
    for (int t = 0; t < CHUNK; t += 2) {
        load_sc(Lb, xb + (size_t)(t + 1) * CONV_DIM, xoff, n0, dtp, t + 1);
        float acc[4];
        step_sc(hs, La, A_h, acc);
        reduce_store(acc, La, D_h, nc, yb + (size_t)t * D_INNER);
        if (t + 2 < CHUNK)
            load_sc(La, xb + (size_t)(t + 2) * CONV_DIM, xoff, n0, dtp, t + 2);
        float acc2[4];
        step_sc(hs, Lb, A_h, acc2);
        reduce_store(acc2, Lb, D_h, nc, yb + (size_t)(t + 1) * D_INNER);
    }
}

// ---------------------------------------------------------------------------
// yg = y * silu(z); rmsnorm(yg) * norm_w -> bf16 output (feeds GEMM2).
// ---------------------------------------------------------------------------
__global__ __launch_bounds__(256) void gate_norm_kernel(
    const float* __restrict__ y,
    const float* __restrict__ zxbcdt,
    const float* __restrict__ norm_w,
    unsigned short* __restrict__ ybf)
{
    const int row = blockIdx.x;
    const int tid = threadIdx.x;
    const float* yr = y + (size_t)row * D_INNER;
    const float* zr = zxbcdt + (size_t)row * D_IN_PROJ;

    float v[8];
    float ss = 0.f;
    #pragma unroll
    for (int j = 0; j < 2; ++j) {
        float4 y4 = *reinterpret_cast<const float4*>(&yr[tid * 8 + j * 4]);
        float4 z4 = *reinterpret_cast<const float4*>(&zr[tid * 8 + j * 4]);
        float a0 = y4.x * siluf(z4.x);
        float a1 = y4.y * siluf(z4.y);
        float a2 = y4.z * siluf(z4.z);
        float a3 = y4.w * siluf(z4.w);
        v[j * 4 + 0] = a0; v[j * 4 + 1] = a1;
        v[j * 4 + 2] = a2; v[j * 4 + 3] = a3;
        ss += a0 * a0 + a1 * a1 + a2 * a2 + a3 * a3;
    }
    #pragma unroll
    for (int o = 1; o < 64; o <<= 1) ss += __shfl_xor(ss, o, 64);
    __shared__ float red[4];
    if ((tid & 63) == 0) red[tid >> 6] = ss;
    __syncthreads();
    const float tot = red[0] + red[1] + red[2] + red[3];
    const float rs = rsqrtf(tot * (1.0f / D_INNER) + EPS);

    const float4* nw = reinterpret_cast<const float4*>(&norm_w[tid * 8]);
    float4 w0 = nw[0], w1 = nw[1];
    u16x8 o;
    o[0] = f2bf(v[0] * rs * w0.x);
    o[1] = f2bf(v[1] * rs * w0.y);
    o[2] = f2bf(v[2] * rs * w0.z);
    o[3] = f2bf(v[3] * rs * w0.w);
    o[4] = f2bf(v[4] * rs * w1.x);
    o[5] = f2bf(v[5] * rs * w1.y);
    o[6] = f2bf(v[6] * rs * w1.z);
    o[7] = f2bf(v[7] * rs * w1.w);
    *reinterpret_cast<u16x8*>(&ybf[(size_t)row * D_INNER + tid * 8]) = o;
}

// ---------------------------------------------------------------------------
extern "C" void kernel_launch(void* const* d_in, const int* in_sizes, int n_in,
                              void* d_out, int out_size, void* d_ws, size_t ws_size,
                              hipStream_t stream)
{
    const float* u       = (const float*)d_in[0];
    const float* W_in    = (const float*)d_in[1];
    const float* conv_w  = (const float*)d_in[2];
    const float* conv_b  = (const float*)d_in[3];
    const float* dt_bias = (const float*)d_in[4];
    const float* A_log   = (const float*)d_in[5];
    const float* Dp      = (const float*)d_in[6];
    const float* norm_w  = (const float*)d_in[7];
    const float* W_out   = (const float*)d_in[8];
    float* out = (float*)d_out;

    float* zxbcdt = (float*)d_ws;                          // 4096*4384 f32
    float* xbc    = zxbcdt + (size_t)BL * D_IN_PROJ;       // 4096*2304 f32
    float* dt_sp  = xbc    + (size_t)BL * CONV_DIM;        // 4096*32 f32
    float* yb     = dt_sp  + (size_t)BL * NHEADS;          // 4096*2048 f32
    float* Sbuf   = yb     + (size_t)BL * D_INNER;         // 8,388,608 f32
    float* alphab = Sbuf   + (size_t)NC * BATCH * NHEADS * HEADDIM * D_STATE;

    // bf16 buffers alias Sbuf across its dead phases.
    unsigned short* ubf  = (unsigned short*)Sbuf;
    unsigned short* wibf = (unsigned short*)Sbuf + (size_t)BL * D_MODEL;
    unsigned short* ybbf = (unsigned short*)Sbuf;
    unsigned short* wobf = (unsigned short*)Sbuf + (size_t)BL * D_INNER;

    // 0. casts for GEMM1
    cast_bf16_kernel<<<(BL * D_MODEL / 8 + 255) / 256, 256, 0, stream>>>(
        u, ubf, BL * D_MODEL / 8);
    cast_win_kernel<<<(N_PAD * D_MODEL / 8 + 255) / 256, 256, 0, stream>>>(
        W_in, wibf);
    // 1. in-projection GEMM (bf16 MFMA)
    {
        dim3 grid(N_PAD / GBM, BL / GBM);
        gemm_bf16_nt<<<grid, 256, 0, stream>>>(
            ubf, wibf, zxbcdt, BL, D_IN_PROJ, D_MODEL, D_IN_PROJ);
    }
    // 2. causal depthwise conv + SiLU
    {
        const int n = BL * CONV_DIM;
        conv_silu_kernel<<<(n + 255) / 256, 256, 0, stream>>>(
            zxbcdt, conv_w, conv_b, xbc);
    }
    // 3. dt = softplus(dt_raw + bias)
    {
        const int n = BL * NHEADS;
        dt_kernel<<<(n + 255) / 256, 256, 0, stream>>>(zxbcdt, dt_bias, dt_sp);
    }
    // 4. chunked SSD scan (4p x 8n per-thread blocks)
    ssd_chunk_state<<<NC * BATCH * NHEADS, 256, 0, stream>>>(
        xbc, dt_sp, A_log, Sbuf, alphab);
    ssd_state_scan<<<BATCH * NHEADS * 4, 256, 0, stream>>>(Sbuf, alphab);
    ssd_chunk_out<<<NC * BATCH * NHEADS, 256, 0, stream>>>(
        xbc, dt_sp, A_log, Dp, Sbuf, yb);
    // 5. cast W_out (aliases Sbuf tail — must follow ssd_chunk_out)
    cast_bf16_kernel<<<(D_MODEL * D_INNER / 8 + 255) / 256, 256, 0, stream>>>(
        W_out, wobf, D_MODEL * D_INNER / 8);
    // 6. gate + RMSNorm -> bf16
    gate_norm_kernel<<<BL, 256, 0, stream>>>(yb, zxbcdt, norm_w, ybbf);
    // 7. out-projection GEMM (bf16 MFMA)
    {
        dim3 grid(D_MODEL / GBM, BL / GBM);
        gemm_bf16_nt<<<grid, 256, 0, stream>>>(
            ybbf, wobf, out, BL, D_MODEL, D_INNER, D_MODEL);
    }
}

// Round 10
// 434.852 us; speedup vs baseline: 6.7692x; 1.1375x over previous
//
#include <hip/hip_runtime.h>
#include <hip/hip_bf16.h>
#include <math.h>
#include <stdint.h>

#define D_MODEL   1024
#define D_INNER   2048
#define HEADDIM   64
#define NHEADS    32
#define D_STATE   128
#define D_CONV    4
#define CONV_DIM  (D_INNER + 2 * D_STATE)          // 2304
#define D_IN_PROJ (2 * D_INNER + 2 * D_STATE + NHEADS) // 4384
#define N_PAD     4480                             // 35 * 128
#define BATCH     2
#define SEQLEN    2048
#define BL        (BATCH * SEQLEN)                 // 4096
#define EPS       1e-5f

#define NC    16
#define CHUNK 128

typedef __bf16 bf16x8 __attribute__((ext_vector_type(8)));
typedef float  f32x4  __attribute__((ext_vector_type(4)));
typedef unsigned short u16x8 __attribute__((ext_vector_type(8)));
typedef unsigned short u16x4 __attribute__((ext_vector_type(4)));

__device__ __forceinline__ float siluf(float x) {
    return x / (1.0f + expf(-x));
}
__device__ __forceinline__ float softplusf(float x) {
    return (x > 20.0f) ? x : log1pf(expf(x));
}
__device__ __forceinline__ unsigned short f2bf(float f) {
    union { float f; unsigned u; } v; v.f = f;
    unsigned r = (v.u + 0x7FFFu + ((v.u >> 16) & 1u)) >> 16;  // RNE
    return (unsigned short)r;
}

// ---------------------------------------------------------------------------
// fp32 -> bf16 cast kernels
// ---------------------------------------------------------------------------
__global__ __launch_bounds__(256) void cast_bf16_kernel(
    const float* __restrict__ in, unsigned short* __restrict__ out, int n8)
{
    const int i = blockIdx.x * 256 + threadIdx.x;
    if (i >= n8) return;
    const float4* p = reinterpret_cast<const float4*>(in + (size_t)i * 8);
    float4 a = p[0], b = p[1];
    u16x8 o;
    o[0] = f2bf(a.x); o[1] = f2bf(a.y); o[2] = f2bf(a.z); o[3] = f2bf(a.w);
    o[4] = f2bf(b.x); o[5] = f2bf(b.y); o[6] = f2bf(b.z); o[7] = f2bf(b.w);
    *reinterpret_cast<u16x8*>(out + (size_t)i * 8) = o;
}

// W_in [4384][1024] -> bf16 padded [4480][1024] (zero rows >= 4384)
__global__ __launch_bounds__(256) void cast_win_kernel(
    const float* __restrict__ W, unsigned short* __restrict__ out)
{
    const int i = blockIdx.x * 256 + threadIdx.x;
    if (i >= N_PAD * D_MODEL / 8) return;
    const int row = i / (D_MODEL / 8);
    u16x8 o;
    if (row < D_IN_PROJ) {
        const float4* p = reinterpret_cast<const float4*>(W + (size_t)i * 8);
        float4 a = p[0], b = p[1];
        o[0] = f2bf(a.x); o[1] = f2bf(a.y); o[2] = f2bf(a.z); o[3] = f2bf(a.w);
        o[4] = f2bf(b.x); o[5] = f2bf(b.y); o[6] = f2bf(b.z); o[7] = f2bf(b.w);
    } else {
        o = (u16x8)(unsigned short)0;
    }
    *reinterpret_cast<u16x8*>(out + (size_t)i * 8) = o;
}

// ---------------------------------------------------------------------------
// bf16 MFMA GEMM (NT) — unchanged (verified Round 6).
// ---------------------------------------------------------------------------
#define GBM 128
#define GBK 32

__device__ __forceinline__ unsigned swz(unsigned o) {
    return o ^ (((o >> 7) & 7u) << 4);
}
// involutory swizzle for 256B-row-stride LDS tiles
__device__ __forceinline__ unsigned swz256(unsigned o) {
    return o ^ (((o >> 8) & 7u) << 4);
}

__device__ __forceinline__ void gld_lds16(const unsigned short* gsrc,
                                          unsigned short* lds) {
    auto* l = reinterpret_cast<__attribute__((address_space(3))) unsigned int*>(
        reinterpret_cast<uintptr_t>(lds));
    const auto* g =
        reinterpret_cast<const __attribute__((address_space(1))) unsigned int*>(
            reinterpret_cast<uintptr_t>(gsrc));
    __builtin_amdgcn_global_load_lds(g, l, 16, 0, 0);
}

__global__ __launch_bounds__(256) void gemm_bf16_nt(
    const unsigned short* __restrict__ A, const unsigned short* __restrict__ B,
    float* __restrict__ C, int M, int N, int K, int ldc)
{
    __shared__ unsigned short As[GBM * GBK];   // 8 KB
    __shared__ unsigned short Bs[GBM * GBK];   // 8 KB

    const int tid = threadIdx.x;
    const int bm = blockIdx.y * GBM;
    const int bn = blockIdx.x * GBM;

    const unsigned d0 = tid * 16;
    const unsigned d1 = 4096 + tid * 16;
    const unsigned o0 = swz(d0), o1 = swz(d1);
    const int r0 = o0 >> 6, c0 = (o0 & 63) >> 1;
    const int r1 = o1 >> 6, c1 = (o1 & 63) >> 1;
    const unsigned short* a_src0 = A + (size_t)(bm + r0) * K + c0;
    const unsigned short* a_src1 = A + (size_t)(bm + r1) * K + c1;
    const unsigned short* b_src0 = B + (size_t)(bn + r0) * K + c0;
    const unsigned short* b_src1 = B + (size_t)(bn + r1) * K + c1;
    unsigned short* a_dst0 = As + (d0 >> 1);
    unsigned short* a_dst1 = As + (d1 >> 1);
    unsigned short* b_dst0 = Bs + (d0 >> 1);
    unsigned short* b_dst1 = Bs + (d1 >> 1);

    const int lane = tid & 63;
    const int wave = tid >> 6;
    const int wr = wave >> 1, wc = wave & 1;
    const int fr = lane & 15;
    const int ko = (lane >> 4) * 8;

    unsigned a_off[4], b_off[4];
    #pragma unroll
    for (int i = 0; i < 4; ++i) {
        a_off[i] = swz(((unsigned)(wr * 64 + i * 16 + fr) << 6) + ko * 2);
        b_off[i] = swz(((unsigned)(wc * 64 + i * 16 + fr) << 6) + ko * 2);
    }

    f32x4 acc[4][4] = {};

    for (int k0 = 0; k0 < K; k0 += GBK) {
        gld_lds16(a_src0, a_dst0);
        gld_lds16(a_src1, a_dst1);
        gld_lds16(b_src0, b_dst0);
        gld_lds16(b_src1, b_dst1);
        __syncthreads();

        bf16x8 af[4], bfr[4];
        #pragma unroll
        for (int i = 0; i < 4; ++i)
            af[i] = *reinterpret_cast<const bf16x8*>(
                reinterpret_cast<const char*>(As) + a_off[i]);
        #pragma unroll
        for (int j = 0; j < 4; ++j)
            bfr[j] = *reinterpret_cast<const bf16x8*>(
                reinterpret_cast<const char*>(Bs) + b_off[j]);
        #pragma unroll
        for (int i = 0; i < 4; ++i)
            #pragma unroll
            for (int j = 0; j < 4; ++j)
                acc[i][j] = __builtin_amdgcn_mfma_f32_16x16x32_bf16(
                    af[i], bfr[j], acc[i][j], 0, 0, 0);
        __syncthreads();
        a_src0 += GBK; a_src1 += GBK; b_src0 += GBK; b_src1 += GBK;
    }

    const int mr = (lane >> 4) * 4;
    #pragma unroll
    for (int i = 0; i < 4; ++i) {
        const int gm = bm + wr * 64 + i * 16 + mr;
        #pragma unroll
        for (int j = 0; j < 4; ++j) {
            const int gn = bn + wc * 64 + j * 16 + fr;
            if (gn < N) {
                #pragma unroll
                for (int r = 0; r < 4; ++r)
                    C[(size_t)(gm + r) * ldc + gn] = acc[i][j][r];
            }
        }
    }
}

// ---------------------------------------------------------------------------
// Causal depthwise conv (K=4) + SiLU over the xBC slice of zxbcdt.
// ---------------------------------------------------------------------------
__global__ __launch_bounds__(256) void conv_silu_kernel(
    const float* __restrict__ zxbcdt, const float* __restrict__ conv_w,
    const float* __restrict__ conv_b, float* __restrict__ xbc_out)
{
    const int idx = blockIdx.x * 256 + threadIdx.x;
    if (idx >= BL * CONV_DIM) return;
    const int c  = idx % CONV_DIM;
    const int bl = idx / CONV_DIM;
    const int l  = bl % SEQLEN;
    const int b  = bl / SEQLEN;

    float acc = conv_b[c];
    #pragma unroll
    for (int k = 0; k < D_CONV; ++k) {
        const int ll = l + k - (D_CONV - 1);
        if (ll >= 0) {
            acc += zxbcdt[(size_t)(b * SEQLEN + ll) * D_IN_PROJ + D_INNER + c]
                   * conv_w[c * D_CONV + k];
        }
    }
    xbc_out[idx] = siluf(acc);
}

// ---------------------------------------------------------------------------
// dt = softplus(dt_raw + dt_bias)
// ---------------------------------------------------------------------------
__global__ __launch_bounds__(256) void dt_kernel(
    const float* __restrict__ zxbcdt, const float* __restrict__ dt_bias,
    float* __restrict__ dt_out)
{
    const int idx = blockIdx.x * 256 + threadIdx.x;
    if (idx >= BL * NHEADS) return;
    const int h  = idx % NHEADS;
    const int bl = idx / NHEADS;
    const float v = zxbcdt[(size_t)bl * D_IN_PROJ + D_INNER + CONV_DIM + h]
                    + dt_bias[h];
    dt_out[idx] = softplusf(v);
}

// ---------------------------------------------------------------------------
// chunk_state + state_scan — unchanged (verified Round 7).
// ---------------------------------------------------------------------------
struct LSa { float4 b0, b1, x4; float d; };

__device__ __forceinline__ void load_sa(LSa& L, const float* __restrict__ row,
                                        int xoff, int n0,
                                        const float* __restrict__ dtp, int t) {
    L.b0 = *reinterpret_cast<const float4*>(&row[D_INNER + n0]);
    L.b1 = *reinterpret_cast<const float4*>(&row[D_INNER + n0 + 4]);
    L.x4 = *reinterpret_cast<const float4*>(&row[xoff]);
    L.d  = dtp[(size_t)t * NHEADS];
}

__device__ __forceinline__ void step_sa(float (&hs)[4][8], const LSa& L,
                                        float A_h, float& sdt) {
    sdt += L.d;
    const float dA = __expf(A_h * L.d);
    const float B[8] = {L.b0.x, L.b0.y, L.b0.z, L.b0.w,
                        L.b1.x, L.b1.y, L.b1.z, L.b1.w};
    const float dtx[4] = {L.d * L.x4.x, L.d * L.x4.y, L.d * L.x4.z, L.d * L.x4.w};
    #pragma unroll
    for (int i = 0; i < 4; ++i)
        #pragma unroll
        for (int j = 0; j < 8; ++j)
            hs[i][j] = hs[i][j] * dA + dtx[i] * B[j];
}

__global__ __launch_bounds__(256) void ssd_chunk_state(
    const float* __restrict__ xbc, const float* __restrict__ dt,
    const float* __restrict__ A_log,
    float* __restrict__ S, float* __restrict__ alpha)
{
    const int bid = blockIdx.x;
    const int h = bid & 31;
    const int b = (bid >> 5) & 1;
    const int c = bid >> 6;
    const int tid = threadIdx.x;
    const int pp = tid >> 4;
    const int nc = tid & 15;
    const int n0 = nc * 8;
    const int xoff = h * HEADDIM + pp * 4;

    const float A_h = -__expf(A_log[h]);
    const float* xb  = xbc + (size_t)(b * SEQLEN + c * CHUNK) * CONV_DIM;
    const float* dtp = dt  + (size_t)(b * SEQLEN + c * CHUNK) * NHEADS + h;

    float hs[4][8] = {};
    float sdt = 0.f;
    LSa La, Lb;
    load_sa(La, xb, xoff, n0, dtp, 0);
    for (int t = 0; t < CHUNK; t += 2) {
        load_sa(Lb, xb + (size_t)(t + 1) * CONV_DIM, xoff, n0, dtp, t + 1);
        step_sa(hs, La, A_h, sdt);
        if (t + 2 < CHUNK)
            load_sa(La, xb + (size_t)(t + 2) * CONV_DIM, xoff, n0, dtp, t + 2);
        step_sa(hs, Lb, A_h, sdt);
    }
    const int cbh = (c * 2 + b) * 32 + h;
    float* Sp = S + (size_t)cbh * 8192 + (size_t)(pp * 4) * 128 + n0;
    #pragma unroll
    for (int i = 0; i < 4; ++i) {
        *reinterpret_cast<float4*>(Sp + i * 128) =
            make_float4(hs[i][0], hs[i][1], hs[i][2], hs[i][3]);
        *reinterpret_cast<float4*>(Sp + i * 128 + 4) =
            make_float4(hs[i][4], hs[i][5], hs[i][6], hs[i][7]);
    }
    if (tid == 0) alpha[cbh] = __expf(A_h * sdt);
}

__global__ __launch_bounds__(256) void ssd_state_scan(
    float* __restrict__ S, const float* __restrict__ alpha)
{
    const int bid = blockIdx.x;       // (b,h,q): q = p-quarter
    const int q = bid & 3;
    const int h = (bid >> 2) & 31;
    const int b = bid >> 7;
    const int tid = threadIdx.x;
    const size_t off = (size_t)(q * 16 + (tid >> 4)) * 128 + (tid & 15) * 8;
    float h0[8] = {};
    #pragma unroll 2
    for (int c = 0; c < NC; ++c) {
        const int cbh = (c * 2 + b) * 32 + h;
        float* Sp = S + (size_t)cbh * 8192 + off;
        const float al = alpha[cbh];
        float4 t0 = *reinterpret_cast<const float4*>(Sp);
        float4 t1 = *reinterpret_cast<const float4*>(Sp + 4);
        *reinterpret_cast<float4*>(Sp)     = make_float4(h0[0], h0[1], h0[2], h0[3]);
        *reinterpret_cast<float4*>(Sp + 4) = make_float4(h0[4], h0[5], h0[6], h0[7]);
        h0[0] = h0[0] * al + t0.x;
        h0[1] = h0[1] * al + t0.y;
        h0[2] = h0[2] * al + t0.z;
        h0[3] = h0[3] * al + t0.w;
        h0[4] = h0[4] * al + t1.x;
        h0[5] = h0[5] * al + t1.y;
        h0[6] = h0[6] * al + t1.z;
        h0[7] = h0[7] * al + t1.w;
    }
}

// ---------------------------------------------------------------------------
// MFMA chunk output.  Per block (b,c,h), 256 thr = 4 waves:
//   lc[t] = A_h * inclusive_prefix(dt)    (wave shfl_up scan)
//   S = C @ B^T           (bf16 MFMA, K=n=128; 2x2 wave quadrants)
//   Y2 = C @ H^T          (K=n; Sbuf [p][n] rows are the B-operand directly)
//   P[t][s] = S * exp(lc[t]-lc[s]) for s<=t else 0   (dt_s folded into Xt)
//   Y1 = P @ Xt^T         (K=s; Xt[p][s] = x[s][p]*dt_s)
//   y[t][p] = Y1 + exp(lc[t]) * Y2        (D*x added later in gate_norm)
// LDS 96.5KB: Bb 32K | Cb->Pb 32K (aliased) | Xt 16K | Hb 16K | lc 512B.
// All tiles 256B row stride, swz256 both-sides swizzle (2-way conflicts only).
// ---------------------------------------------------------------------------
__global__ __launch_bounds__(256) void ssd_chunk_out_mfma(
    const float* __restrict__ xbc, const float* __restrict__ dt,
    const float* __restrict__ A_log, const float* __restrict__ S,
    float* __restrict__ y)
{
    __shared__ __align__(16) unsigned char sm[98824];
    constexpr unsigned OB = 0;         // Bb [128][128] bf16
    constexpr unsigned OC = 32768;     // Cb, later Pb
    constexpr unsigned OX = 65536;     // Xt [64][128] bf16 (x*dt, transposed)
    constexpr unsigned OH = 81920;     // Hb [64][128] bf16
    constexpr unsigned OL = 98304;     // lcf float[128]
    constexpr unsigned OW = 98816;     // wtot float

    const int bid = blockIdx.x;
    const int h = bid & 31;
    const int b = (bid >> 5) & 1;
    const int c = bid >> 6;
    const int tid = threadIdx.x;
    const int lane = tid & 63;
    const int wave = tid >> 6;

    float* lcf  = reinterpret_cast<float*>(sm + OL);
    float* wtot = reinterpret_cast<float*>(sm + OW);

    const float A_h = -__expf(A_log[h]);
    const int row0 = b * SEQLEN + c * CHUNK;
    const float* dtp = dt + (size_t)row0 * NHEADS + h;

    // ---- lc prefix scan (inclusive) over the 128 dt values ----
    float sv = 0.f;
    if (tid < 128) {
        sv = dtp[(size_t)tid * NHEADS];
        #pragma unroll
        for (int o = 1; o < 64; o <<= 1) {
            float u = __shfl_up(sv, o, 64);
            if ((tid & 63) >= o) sv += u;
        }
    }
    if (tid == 63) *wtot = sv;
    __syncthreads();
    if (tid < 128) {
        const float tot = (tid >= 64) ? *wtot : 0.f;
        lcf[tid] = A_h * (sv + tot);
    }

    // ---- stage Bb, Cb (rows t, cols n) ----
    {
        const int r = tid >> 1, half = tid & 1;
        const float* rowB = xbc + (size_t)(row0 + r) * CONV_DIM + D_INNER + half * 64;
        const float* rowC = rowB + D_STATE;
        #pragma unroll
        for (int j = 0; j < 16; ++j) {
            float4 vb = reinterpret_cast<const float4*>(rowB)[j];
            float4 vc = reinterpret_cast<const float4*>(rowC)[j];
            const unsigned o8 = (unsigned)r * 256 + half * 128 + j * 8;
            u16x4 wb = {f2bf(vb.x), f2bf(vb.y), f2bf(vb.z), f2bf(vb.w)};
            u16x4 wc = {f2bf(vc.x), f2bf(vc.y), f2bf(vc.z), f2bf(vc.w)};
            *reinterpret_cast<u16x4*>(sm + OB + swz256(o8)) = wb;
            *reinterpret_cast<u16x4*>(sm + OC + swz256(o8)) = wc;
        }
    }
    // ---- stage Xt[p][s] = x[s][p] * dt_s (transposed, dt folded) ----
    {
        const int s = tid >> 1, ph = (tid & 1) * 32;
        const float dts = dtp[(size_t)s * NHEADS];
        const float* rowX = xbc + (size_t)(row0 + s) * CONV_DIM + h * HEADDIM + ph;
        #pragma unroll
        for (int j = 0; j < 8; ++j) {
            float4 v = reinterpret_cast<const float4*>(rowX)[j];
            const int p0 = ph + j * 4;
            *reinterpret_cast<unsigned short*>(sm + OX + swz256((unsigned)(p0 + 0) * 256 + s * 2)) = f2bf(v.x * dts);
            *reinterpret_cast<unsigned short*>(sm + OX + swz256((unsigned)(p0 + 1) * 256 + s * 2)) = f2bf(v.y * dts);
            *reinterpret_cast<unsigned short*>(sm + OX + swz256((unsigned)(p0 + 2) * 256 + s * 2)) = f2bf(v.z * dts);
            *reinterpret_cast<unsigned short*>(sm + OX + swz256((unsigned)(p0 + 3) * 256 + s * 2)) = f2bf(v.w * dts);
        }
    }
    // ---- stage Hb[p][n] from Sbuf (already [p][n]) ----
    {
        const int cbh = (c * 2 + b) * 32 + h;
        const float* Hp = S + (size_t)cbh * 8192 + tid * 32;
        #pragma unroll
        for (int j = 0; j < 8; ++j) {
            float4 v = reinterpret_cast<const float4*>(Hp)[j];
            const unsigned o8 = (unsigned)tid * 64 + j * 8;
            u16x4 w = {f2bf(v.x), f2bf(v.y), f2bf(v.z), f2bf(v.w)};
            *reinterpret_cast<u16x4*>(sm + OH + swz256(o8)) = w;
        }
    }
    __syncthreads();

    const int fr  = lane & 15;
    const int ko2 = (lane >> 4) * 16;   // byte k-offset within 64B k-step
    const int g   = lane >> 4;

    // ---- S = C @ B^T : wave quadrant (wr:t, wc:s), 64x64 each ----
    const int wr = wave >> 1, wc = wave & 1;
    f32x4 sacc[4][4] = {};
    #pragma unroll
    for (int ks = 0; ks < 4; ++ks) {
        bf16x8 cf[4], bf[4];
        #pragma unroll
        for (int i = 0; i < 4; ++i)
            cf[i] = *reinterpret_cast<const bf16x8*>(sm + OC +
                swz256((unsigned)(wr * 64 + i * 16 + fr) * 256 + ks * 64 + ko2));
        #pragma unroll
        for (int j = 0; j < 4; ++j)
            bf[j] = *reinterpret_cast<const bf16x8*>(sm + OB +
                swz256((unsigned)(wc * 64 + j * 16 + fr) * 256 + ks * 64 + ko2));
        #pragma unroll
        for (int i = 0; i < 4; ++i)
            #pragma unroll
            for (int j = 0; j < 4; ++j)
                sacc[i][j] = __builtin_amdgcn_mfma_f32_16x16x32_bf16(
                    cf[i], bf[j], sacc[i][j], 0, 0, 0);
    }

    // ---- Y2 = C @ H^T : wave strip tw (32 t-rows), K = n ----
    const int tw = wave * 32;
    f32x4 acc2[2][4] = {};
    #pragma unroll
    for (int kn = 0; kn < 4; ++kn) {
        bf16x8 ca[2], hv[4];
        #pragma unroll
        for (int i = 0; i < 2; ++i)
            ca[i] = *reinterpret_cast<const bf16x8*>(sm + OC +
                swz256((unsigned)(tw + i * 16 + fr) * 256 + kn * 64 + ko2));
        #pragma unroll
        for (int j = 0; j < 4; ++j)
            hv[j] = *reinterpret_cast<const bf16x8*>(sm + OH +
                swz256((unsigned)(j * 16 + fr) * 256 + kn * 64 + ko2));
        #pragma unroll
        for (int i = 0; i < 2; ++i)
            #pragma unroll
            for (int j = 0; j < 4; ++j)
                acc2[i][j] = __builtin_amdgcn_mfma_f32_16x16x32_bf16(
                    ca[i], hv[j], acc2[i][j], 0, 0, 0);
    }
    __syncthreads();   // all Cb reads complete before P overwrites it

    // ---- P[t][s] = S * exp(lc[t]-lc[s]), causal; bf16 into OC ----
    #pragma unroll
    for (int i = 0; i < 4; ++i) {
        #pragma unroll
        for (int r = 0; r < 4; ++r) {
            const int t = wr * 64 + i * 16 + g * 4 + r;
            const float lct = lcf[t];
            #pragma unroll
            for (int j = 0; j < 4; ++j) {
                const int s = wc * 64 + j * 16 + fr;
                float pv = 0.f;
                if (s <= t) pv = sacc[i][j][r] * __expf(lct - lcf[s]);
                *reinterpret_cast<unsigned short*>(
                    sm + OC + swz256((unsigned)t * 256 + s * 2)) = f2bf(pv);
            }
        }
    }
    __syncthreads();

    // ---- Y1 = P @ Xt^T : strip tw, K = s ----
    f32x4 acc1[2][4] = {};
    #pragma unroll
    for (int ks = 0; ks < 4; ++ks) {
        bf16x8 pa[2], xv[4];
        #pragma unroll
        for (int i = 0; i < 2; ++i)
            pa[i] = *reinterpret_cast<const bf16x8*>(sm + OC +
                swz256((unsigned)(tw + i * 16 + fr) * 256 + ks * 64 + ko2));
        #pragma unroll
        for (int j = 0; j < 4; ++j)
            xv[j] = *reinterpret_cast<const bf16x8*>(sm + OX +
                swz256((unsigned)(j * 16 + fr) * 256 + ks * 64 + ko2));
        #pragma unroll
        for (int i = 0; i < 2; ++i)
            #pragma unroll
            for (int j = 0; j < 4; ++j)
                acc1[i][j] = __builtin_amdgcn_mfma_f32_16x16x32_bf16(
                    pa[i], xv[j], acc1[i][j], 0, 0, 0);
    }

    // ---- epilogue: y = Y1 + exp(lc[t]) * Y2 ----
    #pragma unroll
    for (int i = 0; i < 2; ++i) {
        #pragma unroll
        for (int r = 0; r < 4; ++r) {
            const int t = tw + i * 16 + g * 4 + r;
            const float el = __expf(lcf[t]);
            float* yrow = y + (size_t)(row0 + t) * D_INNER + h * HEADDIM;
            #pragma unroll
            for (int j = 0; j < 4; ++j)
                yrow[j * 16 + fr] = acc1[i][j][r] + el * acc2[i][j][r];
        }
    }
}

// ---------------------------------------------------------------------------
// yg = (y + D*x) * silu(z); rmsnorm(yg) * norm_w -> bf16 (feeds GEMM2).
// ---------------------------------------------------------------------------
__global__ __launch_bounds__(256) void gate_norm_kernel(
    const float* __restrict__ y,
    const float* __restrict__ zxbcdt,
    const float* __restrict__ xbc,
    const float* __restrict__ Dp,
    const float* __restrict__ norm_w,
    unsigned short* __restrict__ ybf)
{
    const int row = blockIdx.x;
    const int tid = threadIdx.x;
    const float* yr = y + (size_t)row * D_INNER;
    const float* zr = zxbcdt + (size_t)row * D_IN_PROJ;
    const float* xr = xbc + (size_t)row * CONV_DIM;
    const float Dh = Dp[tid >> 3];   // tid*8..tid*8+7 lie within one head

    float v[8];
    float ss = 0.f;
    #pragma unroll
    for (int j = 0; j < 2; ++j) {
        float4 y4 = *reinterpret_cast<const float4*>(&yr[tid * 8 + j * 4]);
        float4 z4 = *reinterpret_cast<const float4*>(&zr[tid * 8 + j * 4]);
        float4 x4 = *reinterpret_cast<const float4*>(&xr[tid * 8 + j * 4]);
        float a0 = (y4.x + Dh * x4.x) * siluf(z4.x);
        float a1 = (y4.y + Dh * x4.y) * siluf(z4.y);
        float a2 = (y4.z + Dh * x4.z) * siluf(z4.z);
        float a3 = (y4.w + Dh * x4.w) * siluf(z4.w);
        v[j * 4 + 0] = a0; v[j * 4 + 1] = a1;
        v[j * 4 + 2] = a2; v[j * 4 + 3] = a3;
        ss += a0 * a0 + a1 * a1 + a2 * a2 + a3 * a3;
    }
    #pragma unroll
    for (int o = 1; o < 64; o <<= 1) ss += __shfl_xor(ss, o, 64);
    __shared__ float red[4];
    if ((tid & 63) == 0) red[tid >> 6] = ss;
    __syncthreads();
    const float tot = red[0] + red[1] + red[2] + red[3];
    const float rs = rsqrtf(tot * (1.0f / D_INNER) + EPS);

    const float4* nw = reinterpret_cast<const float4*>(&norm_w[tid * 8]);
    float4 w0 = nw[0], w1 = nw[1];
    u16x8 o;
    o[0] = f2bf(v[0] * rs * w0.x);
    o[1] = f2bf(v[1] * rs * w0.y);
    o[2] = f2bf(v[2] * rs * w0.z);
    o[3] = f2bf(v[3] * rs * w0.w);
    o[4] = f2bf(v[4] * rs * w1.x);
    o[5] = f2bf(v[5] * rs * w1.y);
    o[6] = f2bf(v[6] * rs * w1.z);
    o[7] = f2bf(v[7] * rs * w1.w);
    *reinterpret_cast<u16x8*>(&ybf[(size_t)row * D_INNER + tid * 8]) = o;
}

// ---------------------------------------------------------------------------
extern "C" void kernel_launch(void* const* d_in, const int* in_sizes, int n_in,
                              void* d_out, int out_size, void* d_ws, size_t ws_size,
                              hipStream_t stream)
{
    const float* u       = (const float*)d_in[0];
    const float* W_in    = (const float*)d_in[1];
    const float* conv_w  = (const float*)d_in[2];
    const float* conv_b  = (const float*)d_in[3];
    const float* dt_bias = (const float*)d_in[4];
    const float* A_log   = (const float*)d_in[5];
    const float* Dp      = (const float*)d_in[6];
    const float* norm_w  = (const float*)d_in[7];
    const float* W_out   = (const float*)d_in[8];
    float* out = (float*)d_out;

    float* zxbcdt = (float*)d_ws;                          // 4096*4384 f32
    float* xbc    = zxbcdt + (size_t)BL * D_IN_PROJ;       // 4096*2304 f32
    float* dt_sp  = xbc    + (size_t)BL * CONV_DIM;        // 4096*32 f32
    float* yb     = dt_sp  + (size_t)BL * NHEADS;          // 4096*2048 f32
    float* Sbuf   = yb     + (size_t)BL * D_INNER;         // 8,388,608 f32
    float* alphab = Sbuf   + (size_t)NC * BATCH * NHEADS * HEADDIM * D_STATE;

    // bf16 buffers alias Sbuf across its dead phases.
    unsigned short* ubf  = (unsigned short*)Sbuf;
    unsigned short* wibf = (unsigned short*)Sbuf + (size_t)BL * D_MODEL;
    unsigned short* ybbf = (unsigned short*)Sbuf;
    unsigned short* wobf = (unsigned short*)Sbuf + (size_t)BL * D_INNER;

    // 0. casts for GEMM1
    cast_bf16_kernel<<<(BL * D_MODEL / 8 + 255) / 256, 256, 0, stream>>>(
        u, ubf, BL * D_MODEL / 8);
    cast_win_kernel<<<(N_PAD * D_MODEL / 8 + 255) / 256, 256, 0, stream>>>(
        W_in, wibf);
    // 1. in-projection GEMM (bf16 MFMA)
    {
        dim3 grid(N_PAD / GBM, BL / GBM);
        gemm_bf16_nt<<<grid, 256, 0, stream>>>(
            ubf, wibf, zxbcdt, BL, D_IN_PROJ, D_MODEL, D_IN_PROJ);
    }
    // 2. causal depthwise conv + SiLU
    {
        const int n = BL * CONV_DIM;
        conv_silu_kernel<<<(n + 255) / 256, 256, 0, stream>>>(
            zxbcdt, conv_w, conv_b, xbc);
    }
    // 3. dt = softplus(dt_raw + bias)
    {
        const int n = BL * NHEADS;
        dt_kernel<<<(n + 255) / 256, 256, 0, stream>>>(zxbcdt, dt_bias, dt_sp);
    }
    // 4. chunked SSD: states (VALU) -> inter-chunk scan -> MFMA chunk output
    ssd_chunk_state<<<NC * BATCH * NHEADS, 256, 0, stream>>>(
        xbc, dt_sp, A_log, Sbuf, alphab);
    ssd_state_scan<<<BATCH * NHEADS * 4, 256, 0, stream>>>(Sbuf, alphab);
    ssd_chunk_out_mfma<<<NC * BATCH * NHEADS, 256, 0, stream>>>(
        xbc, dt_sp, A_log, Sbuf, yb);
    // 5. cast W_out (aliases Sbuf tail — must follow ssd_chunk_out_mfma)
    cast_bf16_kernel<<<(D_MODEL * D_INNER / 8 + 255) / 256, 256, 0, stream>>>(
        W_out, wobf, D_MODEL * D_INNER / 8);
    // 6. gate + RMSNorm (adds D*x) -> bf16
    gate_norm_kernel<<<BL, 256, 0, stream>>>(yb, zxbcdt, xbc, Dp, norm_w, ybbf);
    // 7. out-projection GEMM (bf16 MFMA)
    {
        dim3 grid(D_MODEL / GBM, BL / GBM);
        gemm_bf16_nt<<<grid, 256, 0, stream>>>(
            ybbf, wobf, out, BL, D_MODEL, D_INNER, D_MODEL);
    }
}